// Round 11
// baseline (397.739 us; speedup 1.0000x reference)
//
#include <hip/hip_runtime.h>
#include <hip/hip_bf16.h>

namespace {
constexpr int cS = 16, cB = 16, cC = 256, cH = 4, cDH = 64, cHW = 293;
constexpr int cLQ = cS * cHW;      // 4688
constexpr int cLK = 128;
constexpr int cNN = cLQ * cB;      // 75008
constexpr size_t TX_OFF = 25600;         // 5120 + 16384 + 4096
constexpr size_t HX_OFF = 2122752;       // TX_OFF + 16*16*2*64*64
}

typedef unsigned short ushort_t;
typedef unsigned int uint_t;
typedef __attribute__((ext_vector_type(8))) short short8;    // 8 bf16 (4 VGPRs)
typedef __attribute__((ext_vector_type(4))) float f32x4;     // MFMA C/D frag

__device__ __forceinline__ float bf2f(ushort_t u) {
  return __uint_as_float(((uint_t)u) << 16);
}
__device__ __forceinline__ ushort_t f2bf(float f) {
  __hip_bfloat16 h = __float2bfloat16(f);
  return *(ushort_t*)&h;
}

// SWZ frag-linear activation layout for a [rows][256] matrix:
// element (r, c) -> ((r>>4)*8 + (c>>5))*512 + ((c>>3)&3)*128 + (r&15)*8 + (c&7)
__device__ __forceinline__ size_t swz(int r, int c) {
  return (((size_t)(r >> 4) * 8 + (c >> 5)) * 64 + ((c >> 3) & 3) * 16 + (r & 15)) * 8 + (c & 7);
}

// ============ merged prep: xk cvt+swz, 8 weight swizzles ============
__global__ __launch_bounds__(256) void k_prep(
    const float* __restrict__ xk, ushort_t* __restrict__ xkb,
    const float* __restrict__ wq, ushort_t* __restrict__ wqs,
    const float* __restrict__ wk, ushort_t* __restrict__ wks,
    const float* __restrict__ wv, ushort_t* __restrict__ wvs,
    const float* __restrict__ wo, ushort_t* __restrict__ wos,
    const float* __restrict__ w1, ushort_t* __restrict__ w1s,
    const float* __restrict__ w2, ushort_t* __restrict__ w2s,
    const float* __restrict__ tw, ushort_t* __restrict__ tws,
    const float* __restrict__ hw_, ushort_t* __restrict__ hws)
{
  int bid = blockIdx.x;
  if (bid < 512) {
    int i4 = bid * 256 + threadIdx.x;
    int r = i4 >> 6;
    int c0 = (i4 & 63) * 4;
    float4 v = *(const float4*)(xk + (size_t)r * 256 + c0);
    ushort_t o[4] = {f2bf(v.x), f2bf(v.y), f2bf(v.z), f2bf(v.w)};
    *(uint2*)&xkb[swz(r, c0)] = *(uint2*)o;
    return;
  }
  int rr = bid - 512;
  const float* W; ushort_t* Ws; int N; int lb;
  if      (rr < 32)  { W = wq;  Ws = wqs; N = 256;  lb = rr; }
  else if (rr < 64)  { W = wk;  Ws = wks; N = 256;  lb = rr - 32; }
  else if (rr < 96)  { W = wv;  Ws = wvs; N = 256;  lb = rr - 64; }
  else if (rr < 128) { W = wo;  Ws = wos; N = 256;  lb = rr - 96; }
  else if (rr < 256) { W = w1;  Ws = w1s; N = 1024; lb = rr - 128; }
  else if (rr < 384) { W = w2;  Ws = w2s; N = 256;  lb = rr - 256; }
  else if (rr < 388) { W = tw;  Ws = tws; N = 32;   lb = rr - 384; }
  else               { W = hw_; Ws = hws; N = 32;   lb = rr - 388; }
  int slot = lb * 256 + threadIdx.x;
  int lane = slot & 63;
  int fr   = slot >> 6;
  int NB   = N >> 4;
  int nb   = fr % NB, kc = fr / NB;
  int n    = nb * 16 + (lane & 15);
  int k0   = kc * 32 + (lane >> 4) * 8;
  ushort_t tmp[8];
  #pragma unroll
  for (int i = 0; i < 8; ++i) tmp[i] = f2bf(W[(size_t)(k0 + i) * N + n]);
  *(uint4*)&Ws[(size_t)slot * 8] = *(uint4*)tmp;
}

// ============ core GEMM: 64 rows x (4x16 cols/wave), K=256, N-split waves ============
__device__ __forceinline__ void gemm_k256(
    const ushort_t* __restrict__ A, const ushort_t* __restrict__ Ws,
    int rt0, int slot0, int NB, int lane, f32x4 c[4][4])
{
  #pragma unroll 2
  for (int kc = 0; kc < 8; ++kc) {
    short8 a[4];
    #pragma unroll
    for (int mf = 0; mf < 4; ++mf)
      a[mf] = *(const short8*)(A + (((size_t)(rt0 + mf) * 8 + kc) * 64 + lane) * 8);
    #pragma unroll
    for (int nb = 0; nb < 4; ++nb) {
      short8 b = *(const short8*)(Ws + (((size_t)kc * NB + slot0 + nb) * 64 + lane) * 8);
      #pragma unroll
      for (int mf = 0; mf < 4; ++mf)
        c[mf][nb] = __builtin_amdgcn_mfma_f32_16x16x32_bf16(a[mf], b, c[mf][nb], 0, 0, 0);
    }
  }
}

// ============ merged: fused xq+LN1+Q-projection (bid<1172) OR K/V proj (bid>=1172) ====
__global__ __launch_bounds__(256, 4) void k_qnpkv(
    const int* __restrict__ tq, const float* __restrict__ spatial,
    const float* __restrict__ temporal, const float* __restrict__ g,
    const float* __restrict__ bt, const ushort_t* __restrict__ wqs,
    const float* __restrict__ bq, ushort_t* __restrict__ Out,
    const ushort_t* __restrict__ xkb, const ushort_t* __restrict__ wks,
    const ushort_t* __restrict__ wvs, const float* __restrict__ bk,
    const float* __restrict__ bv, ushort_t* __restrict__ Kb,
    ushort_t* __restrict__ Vb)
{
  __shared__ ushort_t aT[64 * 256];    // A frags, then reused as epilogue tile
  const int NQ = cNN / 64;             // 1172
  const int tid = threadIdx.x, lane = tid & 63, w = tid >> 6;
  const int lane15 = lane & 15, kq = lane >> 4;
  f32x4 z = {0.f, 0.f, 0.f, 0.f};

  if ((int)blockIdx.x >= NQ) {
    // ---- K/V projection path
    int bid2 = blockIdx.x - NQ;        // 0..63
    const ushort_t* Ws = (bid2 >> 5) ? wvs : wks;
    const float* Bi = (bid2 >> 5) ? bv : bk;
    ushort_t* Kv = (bid2 >> 5) ? Vb : Kb;
    const int bx = bid2 & 31;
    const int rt0 = bx * 4, row0 = bx * 64;
    f32x4 c[4][4];
    #pragma unroll
    for (int mf = 0; mf < 4; ++mf)
      #pragma unroll
      for (int nb = 0; nb < 4; ++nb) c[mf][nb] = z;
    gemm_k256(xkb, Ws, rt0, w * 4, 16, lane, c);
    #pragma unroll
    for (int nb = 0; nb < 4; ++nb) {
      int col = w * 64 + nb * 16 + lane15;
      float bias = Bi[col];
      #pragma unroll
      for (int mf = 0; mf < 4; ++mf)
        #pragma unroll
        for (int i = 0; i < 4; ++i) {
          int row = row0 + mf * 16 + kq * 4 + i;
          Kv[(size_t)row * 256 + col] = f2bf(c[mf][nb][i] + bias);
        }
    }
    return;
  }

  // ---- xq + LN1 + Q-projection path
  const int rt0 = blockIdx.x * 4, row0 = blockIdx.x * 64;
  {
    int q = rt0 + w;                   // wave-uniform
    int s = q / cHW, hw = q % cHW;
    int c0 = lane * 4;
    float4 sv = *(const float4*)(spatial + (size_t)hw * cC + c0);
    float4 g4 = *(const float4*)(g + c0);
    float4 b4 = *(const float4*)(bt + c0);
    int kc = c0 >> 5, qq = (c0 >> 3) & 3, joff = c0 & 7;
    for (int rr = 0; rr < 16; ++rr) {
      int t = tq[s * cB + rr];
      float4 tv = *(const float4*)(temporal + (size_t)t * cC + c0);
      float v0 = tv.x + sv.x, v1 = tv.y + sv.y, v2 = tv.z + sv.z, v3 = tv.w + sv.w;
      float sum = v0 + v1 + v2 + v3;
      float sum2 = v0 * v0 + v1 * v1 + v2 * v2 + v3 * v3;
      #pragma unroll
      for (int off = 32; off >= 1; off >>= 1) {
        sum  += __shfl_xor(sum,  off, 64);
        sum2 += __shfl_xor(sum2, off, 64);
      }
      float mean = sum * (1.0f / cC);
      float var  = sum2 * (1.0f / cC) - mean * mean;
      float inv  = rsqrtf(var + 1e-5f);
      ushort_t o[4] = {f2bf((v0 - mean) * inv * g4.x + b4.x),
                       f2bf((v1 - mean) * inv * g4.y + b4.y),
                       f2bf((v2 - mean) * inv * g4.z + b4.z),
                       f2bf((v3 - mean) * inv * g4.w + b4.w)};
      *(uint2*)&aT[(((w * 8 + kc) * 64) + qq * 16 + rr) * 8 + joff] = *(uint2*)o;
    }
  }
  __syncthreads();
  f32x4 c[4][4];
  #pragma unroll
  for (int mf = 0; mf < 4; ++mf)
    #pragma unroll
    for (int nb = 0; nb < 4; ++nb) c[mf][nb] = z;
  gemm_k256(aT, wqs, 0, w * 4, 16, lane, c);
  __syncthreads();                     // all aT frag reads complete
  #pragma unroll
  for (int nb = 0; nb < 4; ++nb) {
    int col = w * 64 + nb * 16 + lane15;
    float bias = bq[col];
    #pragma unroll
    for (int mf = 0; mf < 4; ++mf)
      #pragma unroll
      for (int i = 0; i < 4; ++i)
        aT[(mf * 16 + kq * 4 + i) * 256 + col] = f2bf(c[mf][nb][i] + bias);
  }
  __syncthreads();
  uint2* outp = (uint2*)(Out + (size_t)row0 * 256);
  #pragma unroll
  for (int it = 0; it < 16; ++it) {
    int f = tid + it * 256;
    int row = f >> 6, c0 = (f & 63) * 4;
    outp[f] = *(uint2*)&aT[row * 256 + c0];
  }
}

// ============ MEGA-FUSED: wo proj + xq resid + LN2 + FFN1 + GELU + FFN2 + resid
//              + table/hand heads (fused from k_thg) ====
// R10 base (376.5us total verified). R11 change: the block's A-slice is
// CONTIGUOUS in frag-linear layout (A + row0*256, 32KB) -> stage it once into
// the hLS buffers (coalesced uint4), then phase-1 frags come from LDS instead
// of 8x-redundant global loads (every wave used to load the same 32KB).
// hLS[2] doubles as the h ping-pong after phase 3. +unroll 2 on FFN loops.
__global__ __launch_bounds__(512, 8) void k_woffn(
    const ushort_t* __restrict__ A, const ushort_t* __restrict__ wos,
    const float* __restrict__ bo, const int* __restrict__ tq,
    const float* __restrict__ spatial, const float* __restrict__ temporal,
    const float* __restrict__ g, const float* __restrict__ bt,
    const ushort_t* __restrict__ w1s, const float* __restrict__ b1,
    const ushort_t* __restrict__ w2s, const float* __restrict__ b2,
    ushort_t* __restrict__ x2out,
    const ushort_t* __restrict__ tws, const float* __restrict__ tb,
    const ushort_t* __restrict__ hws, const float* __restrict__ hb,
    float* __restrict__ out)
{
  __shared__ ushort_t aT[64 * 264];     // frag use: first 16384 elems; epilogue stride 264
  __shared__ ushort_t hLS[2][64 * 128]; // A-tile stage (32KB flat) -> h ping/pong
  float (*red)[64][2] = (float (*)[64][2])hLS[0];    // 8*64*2*4 = 4096 B (after phase 1)
  float* meanL = (float*)hLS[0] + 1024;              // +4096 B
  float* invL  = meanL + 64;                         // ends < 16384
  const int tid = threadIdx.x, lane = tid & 63, w = tid >> 6;   // w in [0,8)
  const int lane15 = lane & 15, kq = lane >> 4;
  const int rt0 = blockIdx.x * 4, row0 = blockIdx.x * 64;
  const f32x4 z = {0.f, 0.f, 0.f, 0.f};

  // ---- Stage A-slice (contiguous 32KB, frag-linear) into hLS, coalesced
  {
    const uint4* src = (const uint4*)(A + (size_t)row0 * 256);
    uint4* dst = (uint4*)hLS[0];       // hLS[0]/hLS[1] contiguous
    #pragma unroll
    for (int it = 0; it < 4; ++it)
      dst[tid + it * 512] = src[tid + it * 512];
  }
  __syncthreads();
  const ushort_t* hA = (const ushort_t*)hLS[0];

  // ---- Phase 1: wo GEMM, cc[4][2] over wave's 32 cols; A frags from LDS
  f32x4 cc[4][2];   // wo-GEMM -> residual carrier -> FFN2 accumulates ON TOP
  #pragma unroll
  for (int mf = 0; mf < 4; ++mf)
    #pragma unroll
    for (int nb = 0; nb < 2; ++nb) cc[mf][nb] = z;
  #pragma unroll 2
  for (int kc = 0; kc < 8; ++kc) {
    short8 a[4];
    #pragma unroll
    for (int mf = 0; mf < 4; ++mf)
      a[mf] = *(const short8*)&hA[((mf * 8 + kc) * 64 + lane) * 8];
    #pragma unroll
    for (int nb = 0; nb < 2; ++nb) {
      short8 b = *(const short8*)(wos + (((size_t)kc * 16 + w * 2 + nb) * 64 + lane) * 8);
      #pragma unroll
      for (int mf = 0; mf < 4; ++mf)
        cc[mf][nb] = __builtin_amdgcn_mfma_f32_16x16x32_bf16(a[mf], b, cc[mf][nb], 0, 0, 0);
    }
  }
  // ---- + bias + xq (recomputed): cc now holds the residual x in f32
  {
    int tt[4][4], hws_[4];
    #pragma unroll
    for (int mf = 0; mf < 4; ++mf) {
      int q = rt0 + mf;
      int s = q / cHW;
      hws_[mf] = q % cHW;
      #pragma unroll
      for (int i = 0; i < 4; ++i) tt[mf][i] = tq[s * cB + kq * 4 + i];
    }
    #pragma unroll
    for (int nb = 0; nb < 2; ++nb) {
      int col = w * 32 + nb * 16 + lane15;
      float bias = bo[col];
      #pragma unroll
      for (int mf = 0; mf < 4; ++mf) {
        float sp = spatial[(size_t)hws_[mf] * cC + col];
        #pragma unroll
        for (int i = 0; i < 4; ++i)
          cc[mf][nb][i] += bias + temporal[(size_t)tt[mf][i] * cC + col] + sp;
      }
    }
  }
  __syncthreads();                     // all hA reads done; hLS[0] scratch reusable
  // ---- Phase 2: LN2 stats (cross-wave; scratch aliases hLS[0])
  #pragma unroll
  for (int mf = 0; mf < 4; ++mf)
    #pragma unroll
    for (int i = 0; i < 4; ++i) {
      float s4 = cc[mf][0][i] + cc[mf][1][i];
      float q4 = cc[mf][0][i] * cc[mf][0][i] + cc[mf][1][i] * cc[mf][1][i];
      #pragma unroll
      for (int off = 8; off >= 1; off >>= 1) {
        s4 += __shfl_xor(s4, off, 64);
        q4 += __shfl_xor(q4, off, 64);
      }
      if (lane15 == 0) {
        red[w][mf * 16 + kq * 4 + i][0] = s4;
        red[w][mf * 16 + kq * 4 + i][1] = q4;
      }
    }
  __syncthreads();
  if (tid < 64) {
    float S = 0.f, Q = 0.f;
    #pragma unroll
    for (int ww = 0; ww < 8; ++ww) { S += red[ww][tid][0]; Q += red[ww][tid][1]; }
    float m = S * (1.0f / cC);
    float v = Q * (1.0f / cC) - m * m;
    meanL[tid] = m;
    invL[tid] = rsqrtf(v + 1e-5f);
  }
  __syncthreads();
  // ---- Phase 3: xln -> aT frag layout ONLY (cc keeps x; no global stash)
  #pragma unroll
  for (int nb = 0; nb < 2; ++nb) {
    int col = w * 32 + nb * 16 + lane15;
    float gc = g[col], bc = bt[col];
    int qd = nb * 2 + (lane15 >> 3);   // (col&31)>>3
    int jd = lane15 & 7;
    #pragma unroll
    for (int mf = 0; mf < 4; ++mf)
      #pragma unroll
      for (int i = 0; i < 4; ++i) {
        int rl = mf * 16 + kq * 4 + i;
        float lv = (cc[mf][nb][i] - meanL[rl]) * invL[rl] * gc + bc;
        aT[((mf * 8 + w) * 64 + qd * 16 + kq * 4 + i) * 8 + jd] = f2bf(lv);
      }
  }
  __syncthreads();                     // aT ready; meanL/invL dead (hLS reusable)
  // ---- Phase 4: FFN loop, 8 chunks of 128 h-cols; h ping-pong hLS[0]/hLS[1].
  // One barrier per chunk: GELU-write(c) to buf[c&1] is separated from
  // FFN2(c-2)'s reads of the same buf by barrier(c-1).
  #pragma unroll 1
  for (int hc2 = 0; hc2 < 8; ++hc2) {
    ushort_t* hB = hLS[hc2 & 1];
    // FFN1: wave w computes h cols [hc2*128 + w*16, +16)
    f32x4 c1[4];
    #pragma unroll
    for (int mf = 0; mf < 4; ++mf) c1[mf] = z;
    const int slot = hc2 * 8 + w;
    #pragma unroll 2
    for (int kc = 0; kc < 8; ++kc) {
      short8 a[4];
      #pragma unroll
      for (int mf = 0; mf < 4; ++mf)
        a[mf] = *(const short8*)&aT[((mf * 8 + kc) * 64 + lane) * 8];
      short8 b = *(const short8*)(w1s + (((size_t)kc * 64 + slot) * 64 + lane) * 8);
      #pragma unroll
      for (int mf = 0; mf < 4; ++mf)
        c1[mf] = __builtin_amdgcn_mfma_f32_16x16x32_bf16(a[mf], b, c1[mf], 0, 0, 0);
    }
    // GELU = x * sigmoid(2u) = x / (1 + e^(-2u))  [exact identity]
    {
      int k2g = hc2 * 128 + w * 16 + lane15;    // global h col
      float bias = b1[k2g];
      int kc2l = w >> 1;                        // local (k2&127)>>5
      int kq2 = (w * 2 + (lane15 >> 3)) & 3;    // local (k2>>3)&3
      int j2 = lane15 & 7;
      #pragma unroll
      for (int mf = 0; mf < 4; ++mf)
        #pragma unroll
        for (int i = 0; i < 4; ++i) {
          float xx = c1[mf][i] + bias;
          float x2v = xx * xx;
          float mm = fmaf(x2v, 0.044715f, 1.0f);
          float u2 = xx * mm * -1.5957691216057308f;   // -2*sqrt(2/pi)
          float e = __expf(u2);
          float ge = xx * __builtin_amdgcn_rcpf(1.0f + e);
          hB[((kc2l * 4 + mf) * 64 + kq2 * 16 + kq * 4 + i) * 8 + j2] = f2bf(ge);
        }
    }
    __syncthreads();                  // hB chunk ready
    // FFN2: K=128 (4 kc2), wave cols [w*32,+32), accumulate into cc (resid inside)
    #pragma unroll 2
    for (int kc2 = 0; kc2 < 4; ++kc2) {
      short8 a2[4];
      #pragma unroll
      for (int mf = 0; mf < 4; ++mf)
        a2[mf] = *(const short8*)&hB[((kc2 * 4 + mf) * 64 + lane) * 8];
      #pragma unroll
      for (int nb = 0; nb < 2; ++nb) {
        short8 b = *(const short8*)(w2s +
            (((size_t)(hc2 * 4 + kc2) * 16 + w * 2 + nb) * 64 + lane) * 8);
        #pragma unroll
        for (int mf = 0; mf < 4; ++mf)
          cc[mf][nb] = __builtin_amdgcn_mfma_f32_16x16x32_bf16(a2[mf], b, cc[mf][nb], 0, 0, 0);
      }
    }
  }
  __syncthreads();                     // all aT/hLS frag reads complete
  // ---- Phase 5: cc (= x + FFN) + b2 -> aT row-major STRIDE 264
  #pragma unroll
  for (int nb = 0; nb < 2; ++nb) {
    int col = w * 32 + nb * 16 + lane15;
    float bias = b2[col];
    #pragma unroll
    for (int mf = 0; mf < 4; ++mf)
      #pragma unroll
      for (int i = 0; i < 4; ++i)
        aT[(mf * 16 + kq * 4 + i) * 264 + col] = f2bf(cc[mf][nb][i] + bias);
  }
  __syncthreads();
  // ---- gx-row x2 write (only rows the gx kernel reads: q%293==292)
  #pragma unroll
  for (int mf = 0; mf < 4; ++mf) {
    if ((rt0 + mf) % cHW == 292) {
      for (int f = tid; f < 1024; f += 512) {
        int rl = mf * 16 + (f >> 6), c4 = (f & 63) * 4;
        *(uint2*)&x2out[(size_t)(row0 + rl) * 256 + c4] = *(uint2*)&aT[rl * 264 + c4];
      }
    }
  }
  // ---- fused table/hand heads: waves 0-3 table (rows (w&3)*16), 4-7 hand
  {
    const int wl = w & 3;
    const bool isHand = (w >= 4);
    const ushort_t* Ws = isHand ? hws : tws;
    const float* Bi = isHand ? hb : tb;
    f32x4 ct[2];
    ct[0] = z; ct[1] = z;
    const ushort_t* arow = aT + (wl * 16 + lane15) * 264 + kq * 8;
    #pragma unroll
    for (int kc = 0; kc < 8; ++kc) {
      short8 a = *(const short8*)(arow + kc * 32);
      #pragma unroll
      for (int nb = 0; nb < 2; ++nb) {
        short8 bf_ = *(const short8*)(Ws + (((size_t)(kc * 2 + nb)) * 64 + lane) * 8);
        ct[nb] = __builtin_amdgcn_mfma_f32_16x16x32_bf16(a, bf_, ct[nb], 0, 0, 0);
      }
    }
    #pragma unroll
    for (int nb = 0; nb < 2; ++nb) {
      int j = nb * 16 + lane15;
      float bias = Bi[j];
      int uh = j >> 3, uw = (j >> 1) & 3, uc = j & 1;
      #pragma unroll
      for (int i = 0; i < 4; ++i) {
        int rg = row0 + wl * 16 + kq * 4 + i;
        int b = rg & 15, q = rg >> 4;
        int s = (q * 3579) >> 20;          // exact q/293 for q<14768
        int hw = q - s * cHW;
        if (!isHand && hw < 256) {
          int th = hw >> 4, twi = hw & 15;
          size_t idx = TX_OFF +
              ((((size_t)(s * cB + b)) * 2 + uc) * 64 + (th * 4 + uh)) * 64 + (twi * 4 + uw);
          out[idx] = ct[nb][i] + bias;
        } else if (isHand && hw >= 256 && hw < 292) {
          int h2 = hw - 256;
          int hh = h2 / 6, ww = h2 % 6;
          size_t idx = HX_OFF +
              ((((size_t)(s * cB + b)) * 2 + uc) * 24 + (hh * 4 + uh)) * 24 + (ww * 4 + uw);
          out[idx] = ct[nb][i] + bias;
        }
      }
    }
  }
}

// ============ MFMA attention: 512 threads, per (b,h), 16 q-tiles per block ============
__global__ __launch_bounds__(512, 4) void k_attn(
    const ushort_t* __restrict__ Qb, const ushort_t* __restrict__ Kb,
    const ushort_t* __restrict__ Vb, const int* __restrict__ tq,
    const int* __restrict__ tk, const int* __restrict__ pad_q,
    const int* __restrict__ pad_k, ushort_t* __restrict__ aout)
{
  __shared__ ushort_t KL[128 * 72];     // [k][d]
  __shared__ ushort_t VtL[64 * 136];    // [d][k]
  __shared__ ushort_t pL[8][16 * 136];  // per-wave P tile
  __shared__ int tkL[128];

  const int h = blockIdx.y, b = blockIdx.z;
  const int tid = threadIdx.x, lane = tid & 63, w = tid >> 6;   // w in [0,8)
  const int m15 = lane & 15, quad = lane >> 4;

  for (int i = tid; i < 128 * 16; i += 512) {
    int k = i >> 4, d4 = (i & 15) * 4;
    size_t src = (size_t)(k * cB + b) * 256 + h * 64 + d4;
    uint2 kv = *(const uint2*)&Kb[src];
    uint2 vv = *(const uint2*)&Vb[src];
    *(uint2*)&KL[k * 72 + d4] = kv;
    const ushort_t* vvp = (const ushort_t*)&vv;
    #pragma unroll
    for (int t = 0; t < 4; ++t) VtL[(d4 + t) * 136 + k] = vvp[t];
  }
  if (tid < 128) tkL[tid] = tk[tid * cB + b];
  __syncthreads();
  const int pk = pad_k[b];
  const int pq = pad_q[b] * cHW;
  ushort_t* pRow = pL[w];
  const f32x4 z = {0.f, 0.f, 0.f, 0.f};

  for (int pr = 0; pr < 2; ++pr) {
    int qt = blockIdx.x * 16 + pr * 8 + w;
    if (qt >= 293) break;                       // wave-uniform
    const ushort_t* qrow =
        Qb + ((size_t)((qt * 16 + m15) * cB + b)) * 256 + h * 64 + quad * 8;
    short8 qa0 = *(const short8*)(qrow);
    short8 qa1 = *(const short8*)(qrow + 32);
    f32x4 s[8];
    #pragma unroll
    for (int nf = 0; nf < 8; ++nf) {
      const ushort_t* kp = KL + (nf * 16 + m15) * 72 + quad * 8;
      short8 b0 = *(const short8*)(kp);
      short8 b1 = *(const short8*)(kp + 32);
      s[nf] = __builtin_amdgcn_mfma_f32_16x16x32_bf16(qa0, b0, z, 0, 0, 0);
      s[nf] = __builtin_amdgcn_mfma_f32_16x16x32_bf16(qa1, b1, s[nf], 0, 0, 0);
    }
    int tqv[4], qok[4];
    #pragma unroll
    for (int i = 0; i < 4; ++i) {
      int qg = qt * 16 + quad * 4 + i;
      int sidx = (qg * 3579) >> 20;            // exact q/293 for q<14768
      tqv[i] = tq[sidx * cB + b];
      qok[i] = (qg < pq);
    }
    #pragma unroll
    for (int nf = 0; nf < 8; ++nf) {
      int kidx = nf * 16 + m15;
      int tkc = tkL[kidx];
      bool kok = (kidx < pk);
      #pragma unroll
      for (int i = 0; i < 4; ++i) {
        bool ok = kok && qok[i] && (tkc <= tqv[i]);
        s[nf][i] = ok ? s[nf][i] * 0.125f : -1e9f;
      }
    }
    float mx[4], l[4];
    #pragma unroll
    for (int i = 0; i < 4; ++i) {
      float m = s[0][i];
      #pragma unroll
      for (int nf = 1; nf < 8; ++nf) m = fmaxf(m, s[nf][i]);
      #pragma unroll
      for (int off = 8; off >= 1; off >>= 1) m = fmaxf(m, __shfl_xor(m, off, 64));
      mx[i] = m;
    }
    #pragma unroll
    for (int i = 0; i < 4; ++i) l[i] = 0.f;
    #pragma unroll
    for (int nf = 0; nf < 8; ++nf)
      #pragma unroll
      for (int i = 0; i < 4; ++i) {
        float p = __expf(s[nf][i] - mx[i]);
        s[nf][i] = p;
        l[i] += p;
      }
    #pragma unroll
    for (int i = 0; i < 4; ++i) {
      float t = l[i];
      #pragma unroll
      for (int off = 8; off >= 1; off >>= 1) t += __shfl_xor(t, off, 64);
      l[i] = 1.0f / t;
    }
    #pragma unroll
    for (int nf = 0; nf < 8; ++nf)
      #pragma unroll
      for (int i = 0; i < 4; ++i)
        pRow[(quad * 4 + i) * 136 + nf * 16 + m15] = f2bf(s[nf][i]);
    f32x4 o[4];
    #pragma unroll
    for (int nf = 0; nf < 4; ++nf) o[nf] = z;
    #pragma unroll
    for (int kc = 0; kc < 4; ++kc) {
      short8 pa = *(const short8*)(pRow + m15 * 136 + kc * 32 + quad * 8);
      #pragma unroll
      for (int nf = 0; nf < 4; ++nf) {
        short8 vb = *(const short8*)(VtL + (nf * 16 + m15) * 136 + kc * 32 + quad * 8);
        o[nf] = __builtin_amdgcn_mfma_f32_16x16x32_bf16(pa, vb, o[nf], 0, 0, 0);
      }
    }
    #pragma unroll
    for (int nf = 0; nf < 4; ++nf) {
      int c = h * 64 + nf * 16 + m15;
      size_t base = ((size_t)(c >> 5)) * 64 + ((c >> 3) & 3) * 16 + b;
      int cj = c & 7;
      #pragma unroll
      for (int i = 0; i < 4; ++i) {
        int qg = qt * 16 + quad * 4 + i;
        aout[(((size_t)qg * 8) * 64 + base) * 8 + cj] = f2bf(o[nf][i] * l[i]);
      }
    }
  }
}

// ============ gx heads only (table/hand heads fused into k_woffn) ============
__global__ __launch_bounds__(256, 4) void k_thg(
    const ushort_t* __restrict__ x2,
    const float* __restrict__ mw, const float* __restrict__ mbi,
    const float* __restrict__ sw, const float* __restrict__ sbi,
    const float* __restrict__ cw, const float* __restrict__ cbi,
    float* __restrict__ out)
{
  __shared__ float rowL[256];
  const int tid = threadIdx.x;
  int sb = blockIdx.x;                 // s*16 + b
  int s = sb >> 4, b = sb & 15;
  const ushort_t* row = x2 + ((size_t)(s * cHW + 292) * cB + b) * cC;
  rowL[tid] = bf2f(row[tid]);
  __syncthreads();
  int j = tid;
  if (j < 100) {
    const float* W;
    const float* Bi;
    int jj, M;
    size_t off;
    if (j < 20)      { W = mw; Bi = mbi; jj = j;      M = 20; off = 0;     }
    else if (j < 84) { W = sw; Bi = sbi; jj = j - 20; M = 64; off = 5120;  }
    else             { W = cw; Bi = cbi; jj = j - 84; M = 16; off = 21504; }
    float acc = Bi[jj];
    for (int c = 0; c < 256; ++c) acc = fmaf(rowL[c], W[c * M + jj], acc);
    out[off + (size_t)sb * M + jj] = acc;
  }
}

extern "C" void kernel_launch(void* const* d_in, const int* in_sizes, int n_in,
                              void* d_out, int out_size, void* d_ws, size_t ws_size,
                              hipStream_t stream)
{
  const int*   tq       = (const int*)d_in[0];
  const int*   pad_q    = (const int*)d_in[1];
  const float* xk       = (const float*)d_in[2];
  const int*   tk       = (const int*)d_in[3];
  const int*   pad_k    = (const int*)d_in[4];
  const float* spatial  = (const float*)d_in[8];
  const float* temporal = (const float*)d_in[9];
  const float* ln1_g    = (const float*)d_in[10];
  const float* ln1_b    = (const float*)d_in[11];
  const float* wq       = (const float*)d_in[12];
  const float* bq       = (const float*)d_in[13];
  const float* wk       = (const float*)d_in[14];
  const float* bk       = (const float*)d_in[15];
  const float* wv       = (const float*)d_in[16];
  const float* bv       = (const float*)d_in[17];
  const float* wo       = (const float*)d_in[18];
  const float* bo       = (const float*)d_in[19];
  const float* ln2_g    = (const float*)d_in[20];
  const float* ln2_b    = (const float*)d_in[21];
  const float* w1       = (const float*)d_in[22];
  const float* b1       = (const float*)d_in[23];
  const float* w2       = (const float*)d_in[24];
  const float* b2       = (const float*)d_in[25];
  const float* table_w  = (const float*)d_in[26];
  const float* table_b  = (const float*)d_in[27];
  const float* hand_w   = (const float*)d_in[28];
  const float* hand_b   = (const float*)d_in[29];
  const float* mode_w   = (const float*)d_in[30];
  const float* mode_b   = (const float*)d_in[31];
  const float* shape_w  = (const float*)d_in[32];
  const float* shape_b  = (const float*)d_in[33];
  const float* color_w  = (const float*)d_in[34];
  const float* color_b  = (const float*)d_in[35];
  float* out = (float*)d_out;

  char* ws = (char*)d_ws;
  const size_t NB2 = (size_t)cNN * cC * sizeof(ushort_t);      // 38,404,096
  ushort_t* buf1 = (ushort_t*)ws;                              // a_swz (attn out)
  ushort_t* buf2 = (ushort_t*)(ws + NB2);                      // Q -> x2 (gx rows)
  char* p = ws + 2 * NB2;
  ushort_t* Kb  = (ushort_t*)p;  p += (size_t)cLK * cB * 256 * 2;
  ushort_t* Vb  = (ushort_t*)p;  p += (size_t)cLK * cB * 256 * 2;
  ushort_t* xkb = (ushort_t*)p;  p += (size_t)cLK * cB * 256 * 2;
  ushort_t* wqs = (ushort_t*)p;  p += 256 * 256 * 2;
  ushort_t* wks = (ushort_t*)p;  p += 256 * 256 * 2;
  ushort_t* wvs = (ushort_t*)p;  p += 256 * 256 * 2;
  ushort_t* wos = (ushort_t*)p;  p += 256 * 256 * 2;
  ushort_t* w1s = (ushort_t*)p;  p += 256 * 1024 * 2;
  ushort_t* w2s = (ushort_t*)p;  p += 1024 * 256 * 2;
  ushort_t* tws = (ushort_t*)p;  p += 256 * 32 * 2;
  ushort_t* hws = (ushort_t*)p;  p += 256 * 32 * 2;

  k_prep<<<904, 256, 0, stream>>>(xk, xkb, wq, wqs, wk, wks, wv, wvs,
                                  wo, wos, w1, w1s, w2, w2s,
                                  table_w, tws, hand_w, hws);
  k_qnpkv<<<cNN / 64 + 64, 256, 0, stream>>>(tq, spatial, temporal, ln1_g, ln1_b,
                                             wqs, bq, buf2, xkb, wks, wvs,
                                             bk, bv, Kb, Vb);
  k_attn<<<dim3(19, cH, cB), 512, 0, stream>>>(buf2, Kb, Vb, tq, tk,
                                               pad_q, pad_k, buf1);
  k_woffn<<<cNN / 64, 512, 0, stream>>>(buf1, wos, bo, tq, spatial, temporal,
                                        ln2_g, ln2_b, w1s, b1, w2s, b2, buf2,
                                        tws, table_b, hws, hand_b, out);
  k_thg<<<cS * cB, 256, 0, stream>>>(buf2, mode_w, mode_b, shape_w, shape_b,
                                     color_w, color_b, out);
}

// Round 12
// 376.246 us; speedup vs baseline: 1.0571x; 1.0571x over previous
//
#include <hip/hip_runtime.h>
#include <hip/hip_bf16.h>

namespace {
constexpr int cS = 16, cB = 16, cC = 256, cH = 4, cDH = 64, cHW = 293;
constexpr int cLQ = cS * cHW;      // 4688
constexpr int cLK = 128;
constexpr int cNN = cLQ * cB;      // 75008
constexpr size_t TX_OFF = 25600;         // 5120 + 16384 + 4096
constexpr size_t HX_OFF = 2122752;       // TX_OFF + 16*16*2*64*64
}

typedef unsigned short ushort_t;
typedef unsigned int uint_t;
typedef __attribute__((ext_vector_type(8))) short short8;    // 8 bf16 (4 VGPRs)
typedef __attribute__((ext_vector_type(4))) float f32x4;     // MFMA C/D frag

__device__ __forceinline__ float bf2f(ushort_t u) {
  return __uint_as_float(((uint_t)u) << 16);
}
__device__ __forceinline__ ushort_t f2bf(float f) {
  __hip_bfloat16 h = __float2bfloat16(f);
  return *(ushort_t*)&h;
}

// SWZ frag-linear activation layout for a [rows][256] matrix:
// element (r, c) -> ((r>>4)*8 + (c>>5))*512 + ((c>>3)&3)*128 + (r&15)*8 + (c&7)
__device__ __forceinline__ size_t swz(int r, int c) {
  return (((size_t)(r >> 4) * 8 + (c >> 5)) * 64 + ((c >> 3) & 3) * 16 + (r & 15)) * 8 + (c & 7);
}

// ============ merged prep: xk cvt+swz, 8 weight swizzles ============
__global__ __launch_bounds__(256) void k_prep(
    const float* __restrict__ xk, ushort_t* __restrict__ xkb,
    const float* __restrict__ wq, ushort_t* __restrict__ wqs,
    const float* __restrict__ wk, ushort_t* __restrict__ wks,
    const float* __restrict__ wv, ushort_t* __restrict__ wvs,
    const float* __restrict__ wo, ushort_t* __restrict__ wos,
    const float* __restrict__ w1, ushort_t* __restrict__ w1s,
    const float* __restrict__ w2, ushort_t* __restrict__ w2s,
    const float* __restrict__ tw, ushort_t* __restrict__ tws,
    const float* __restrict__ hw_, ushort_t* __restrict__ hws)
{
  int bid = blockIdx.x;
  if (bid < 512) {
    int i4 = bid * 256 + threadIdx.x;
    int r = i4 >> 6;
    int c0 = (i4 & 63) * 4;
    float4 v = *(const float4*)(xk + (size_t)r * 256 + c0);
    ushort_t o[4] = {f2bf(v.x), f2bf(v.y), f2bf(v.z), f2bf(v.w)};
    *(uint2*)&xkb[swz(r, c0)] = *(uint2*)o;
    return;
  }
  int rr = bid - 512;
  const float* W; ushort_t* Ws; int N; int lb;
  if      (rr < 32)  { W = wq;  Ws = wqs; N = 256;  lb = rr; }
  else if (rr < 64)  { W = wk;  Ws = wks; N = 256;  lb = rr - 32; }
  else if (rr < 96)  { W = wv;  Ws = wvs; N = 256;  lb = rr - 64; }
  else if (rr < 128) { W = wo;  Ws = wos; N = 256;  lb = rr - 96; }
  else if (rr < 256) { W = w1;  Ws = w1s; N = 1024; lb = rr - 128; }
  else if (rr < 384) { W = w2;  Ws = w2s; N = 256;  lb = rr - 256; }
  else if (rr < 388) { W = tw;  Ws = tws; N = 32;   lb = rr - 384; }
  else               { W = hw_; Ws = hws; N = 32;   lb = rr - 388; }
  int slot = lb * 256 + threadIdx.x;
  int lane = slot & 63;
  int fr   = slot >> 6;
  int NB   = N >> 4;
  int nb   = fr % NB, kc = fr / NB;
  int n    = nb * 16 + (lane & 15);
  int k0   = kc * 32 + (lane >> 4) * 8;
  ushort_t tmp[8];
  #pragma unroll
  for (int i = 0; i < 8; ++i) tmp[i] = f2bf(W[(size_t)(k0 + i) * N + n]);
  *(uint4*)&Ws[(size_t)slot * 8] = *(uint4*)tmp;
}

// ============ core GEMM: 64 rows x (4x16 cols/wave), K=256, N-split waves ============
__device__ __forceinline__ void gemm_k256(
    const ushort_t* __restrict__ A, const ushort_t* __restrict__ Ws,
    int rt0, int slot0, int NB, int lane, f32x4 c[4][4])
{
  #pragma unroll 2
  for (int kc = 0; kc < 8; ++kc) {
    short8 a[4];
    #pragma unroll
    for (int mf = 0; mf < 4; ++mf)
      a[mf] = *(const short8*)(A + (((size_t)(rt0 + mf) * 8 + kc) * 64 + lane) * 8);
    #pragma unroll
    for (int nb = 0; nb < 4; ++nb) {
      short8 b = *(const short8*)(Ws + (((size_t)kc * NB + slot0 + nb) * 64 + lane) * 8);
      #pragma unroll
      for (int mf = 0; mf < 4; ++mf)
        c[mf][nb] = __builtin_amdgcn_mfma_f32_16x16x32_bf16(a[mf], b, c[mf][nb], 0, 0, 0);
    }
  }
}

// ============ merged: fused xq+LN1+Q-projection (bid<1172) OR K/V proj (bid>=1172) ====
__global__ __launch_bounds__(256, 4) void k_qnpkv(
    const int* __restrict__ tq, const float* __restrict__ spatial,
    const float* __restrict__ temporal, const float* __restrict__ g,
    const float* __restrict__ bt, const ushort_t* __restrict__ wqs,
    const float* __restrict__ bq, ushort_t* __restrict__ Out,
    const ushort_t* __restrict__ xkb, const ushort_t* __restrict__ wks,
    const ushort_t* __restrict__ wvs, const float* __restrict__ bk,
    const float* __restrict__ bv, ushort_t* __restrict__ Kb,
    ushort_t* __restrict__ Vb)
{
  __shared__ ushort_t aT[64 * 256];    // A frags, then reused as epilogue tile
  const int NQ = cNN / 64;             // 1172
  const int tid = threadIdx.x, lane = tid & 63, w = tid >> 6;
  const int lane15 = lane & 15, kq = lane >> 4;
  f32x4 z = {0.f, 0.f, 0.f, 0.f};

  if ((int)blockIdx.x >= NQ) {
    // ---- K/V projection path
    int bid2 = blockIdx.x - NQ;        // 0..63
    const ushort_t* Ws = (bid2 >> 5) ? wvs : wks;
    const float* Bi = (bid2 >> 5) ? bv : bk;
    ushort_t* Kv = (bid2 >> 5) ? Vb : Kb;
    const int bx = bid2 & 31;
    const int rt0 = bx * 4, row0 = bx * 64;
    f32x4 c[4][4];
    #pragma unroll
    for (int mf = 0; mf < 4; ++mf)
      #pragma unroll
      for (int nb = 0; nb < 4; ++nb) c[mf][nb] = z;
    gemm_k256(xkb, Ws, rt0, w * 4, 16, lane, c);
    #pragma unroll
    for (int nb = 0; nb < 4; ++nb) {
      int col = w * 64 + nb * 16 + lane15;
      float bias = Bi[col];
      #pragma unroll
      for (int mf = 0; mf < 4; ++mf)
        #pragma unroll
        for (int i = 0; i < 4; ++i) {
          int row = row0 + mf * 16 + kq * 4 + i;
          Kv[(size_t)row * 256 + col] = f2bf(c[mf][nb][i] + bias);
        }
    }
    return;
  }

  // ---- xq + LN1 + Q-projection path
  const int rt0 = blockIdx.x * 4, row0 = blockIdx.x * 64;
  {
    int q = rt0 + w;                   // wave-uniform
    int s = q / cHW, hw = q % cHW;
    int c0 = lane * 4;
    float4 sv = *(const float4*)(spatial + (size_t)hw * cC + c0);
    float4 g4 = *(const float4*)(g + c0);
    float4 b4 = *(const float4*)(bt + c0);
    int kc = c0 >> 5, qq = (c0 >> 3) & 3, joff = c0 & 7;
    for (int rr = 0; rr < 16; ++rr) {
      int t = tq[s * cB + rr];
      float4 tv = *(const float4*)(temporal + (size_t)t * cC + c0);
      float v0 = tv.x + sv.x, v1 = tv.y + sv.y, v2 = tv.z + sv.z, v3 = tv.w + sv.w;
      float sum = v0 + v1 + v2 + v3;
      float sum2 = v0 * v0 + v1 * v1 + v2 * v2 + v3 * v3;
      #pragma unroll
      for (int off = 32; off >= 1; off >>= 1) {
        sum  += __shfl_xor(sum,  off, 64);
        sum2 += __shfl_xor(sum2, off, 64);
      }
      float mean = sum * (1.0f / cC);
      float var  = sum2 * (1.0f / cC) - mean * mean;
      float inv  = rsqrtf(var + 1e-5f);
      ushort_t o[4] = {f2bf((v0 - mean) * inv * g4.x + b4.x),
                       f2bf((v1 - mean) * inv * g4.y + b4.y),
                       f2bf((v2 - mean) * inv * g4.z + b4.z),
                       f2bf((v3 - mean) * inv * g4.w + b4.w)};
      *(uint2*)&aT[(((w * 8 + kc) * 64) + qq * 16 + rr) * 8 + joff] = *(uint2*)o;
    }
  }
  __syncthreads();
  f32x4 c[4][4];
  #pragma unroll
  for (int mf = 0; mf < 4; ++mf)
    #pragma unroll
    for (int nb = 0; nb < 4; ++nb) c[mf][nb] = z;
  gemm_k256(aT, wqs, 0, w * 4, 16, lane, c);
  __syncthreads();                     // all aT frag reads complete
  #pragma unroll
  for (int nb = 0; nb < 4; ++nb) {
    int col = w * 64 + nb * 16 + lane15;
    float bias = bq[col];
    #pragma unroll
    for (int mf = 0; mf < 4; ++mf)
      #pragma unroll
      for (int i = 0; i < 4; ++i)
        aT[(mf * 16 + kq * 4 + i) * 256 + col] = f2bf(c[mf][nb][i] + bias);
  }
  __syncthreads();
  uint2* outp = (uint2*)(Out + (size_t)row0 * 256);
  #pragma unroll
  for (int it = 0; it < 16; ++it) {
    int f = tid + it * 256;
    int row = f >> 6, c0 = (f & 63) * 4;
    outp[f] = *(uint2*)&aT[row * 256 + c0];
  }
}

// ============ MEGA-FUSED: wo proj + xq resid + LN2 + FFN1 + GELU + FFN2 + resid
//              + table/hand heads (fused from k_thg) ====
// R10 configuration (verified 376.5us total, k_woffn 184us): R1 structure +
// FFN2-accumulates-into-residual-cc + hL ping-pong (1 barrier/chunk) + fused
// table/hand heads with stride-264 epilogue staging. R11 lesson: A-LDS-staging
// + unroll-2 pushed VGPR 64->68 and occupancy 36->21% (2->1 blocks/CU);
// 2-block co-residency beats single-block load dedup here. Do not deepen
// per-block pipelining in this kernel.
__global__ __launch_bounds__(512, 8) void k_woffn(
    const ushort_t* __restrict__ A, const ushort_t* __restrict__ wos,
    const float* __restrict__ bo, const int* __restrict__ tq,
    const float* __restrict__ spatial, const float* __restrict__ temporal,
    const float* __restrict__ g, const float* __restrict__ bt,
    const ushort_t* __restrict__ w1s, const float* __restrict__ b1,
    const ushort_t* __restrict__ w2s, const float* __restrict__ b2,
    ushort_t* __restrict__ x2out,
    const ushort_t* __restrict__ tws, const float* __restrict__ tb,
    const ushort_t* __restrict__ hws, const float* __restrict__ hb,
    float* __restrict__ out)
{
  __shared__ ushort_t aT[64 * 264];     // frag use: first 16384 elems; epilogue stride 264
  __shared__ ushort_t hL0[64 * 128];    // h ping buffer (16KB); LN2 scratch aliased
  __shared__ ushort_t hL1[64 * 128];    // h pong buffer (16KB)
  float (*red)[64][2] = (float (*)[64][2])hL0;       // 8*64*2*4 = 4096 B
  float* meanL = (float*)hL0 + 1024;                 // +4096 B
  float* invL  = meanL + 64;                         // ends < 16384
  const int tid = threadIdx.x, lane = tid & 63, w = tid >> 6;   // w in [0,8)
  const int lane15 = lane & 15, kq = lane >> 4;
  const int rt0 = blockIdx.x * 4, row0 = blockIdx.x * 64;
  const f32x4 z = {0.f, 0.f, 0.f, 0.f};

  // ---- Phase 1: wo GEMM, cc[4][2] over wave's 32 cols
  f32x4 cc[4][2];   // wo-GEMM -> residual carrier -> FFN2 accumulates ON TOP
  #pragma unroll
  for (int mf = 0; mf < 4; ++mf)
    #pragma unroll
    for (int nb = 0; nb < 2; ++nb) cc[mf][nb] = z;
  #pragma unroll 1
  for (int kc = 0; kc < 8; ++kc) {
    short8 a[4];
    #pragma unroll
    for (int mf = 0; mf < 4; ++mf)
      a[mf] = *(const short8*)(A + (((size_t)(rt0 + mf) * 8 + kc) * 64 + lane) * 8);
    #pragma unroll
    for (int nb = 0; nb < 2; ++nb) {
      short8 b = *(const short8*)(wos + (((size_t)kc * 16 + w * 2 + nb) * 64 + lane) * 8);
      #pragma unroll
      for (int mf = 0; mf < 4; ++mf)
        cc[mf][nb] = __builtin_amdgcn_mfma_f32_16x16x32_bf16(a[mf], b, cc[mf][nb], 0, 0, 0);
    }
  }
  // ---- + bias + xq (recomputed): cc now holds the residual x in f32
  {
    int tt[4][4], hws_[4];
    #pragma unroll
    for (int mf = 0; mf < 4; ++mf) {
      int q = rt0 + mf;
      int s = q / cHW;
      hws_[mf] = q % cHW;
      #pragma unroll
      for (int i = 0; i < 4; ++i) tt[mf][i] = tq[s * cB + kq * 4 + i];
    }
    #pragma unroll
    for (int nb = 0; nb < 2; ++nb) {
      int col = w * 32 + nb * 16 + lane15;
      float bias = bo[col];
      #pragma unroll
      for (int mf = 0; mf < 4; ++mf) {
        float sp = spatial[(size_t)hws_[mf] * cC + col];
        #pragma unroll
        for (int i = 0; i < 4; ++i)
          cc[mf][nb][i] += bias + temporal[(size_t)tt[mf][i] * cC + col] + sp;
      }
    }
  }
  // ---- Phase 2: LN2 stats (cross-wave; scratch lives in hL0 alias)
  #pragma unroll
  for (int mf = 0; mf < 4; ++mf)
    #pragma unroll
    for (int i = 0; i < 4; ++i) {
      float s4 = cc[mf][0][i] + cc[mf][1][i];
      float q4 = cc[mf][0][i] * cc[mf][0][i] + cc[mf][1][i] * cc[mf][1][i];
      #pragma unroll
      for (int off = 8; off >= 1; off >>= 1) {
        s4 += __shfl_xor(s4, off, 64);
        q4 += __shfl_xor(q4, off, 64);
      }
      if (lane15 == 0) {
        red[w][mf * 16 + kq * 4 + i][0] = s4;
        red[w][mf * 16 + kq * 4 + i][1] = q4;
      }
    }
  __syncthreads();
  if (tid < 64) {
    float S = 0.f, Q = 0.f;
    #pragma unroll
    for (int ww = 0; ww < 8; ++ww) { S += red[ww][tid][0]; Q += red[ww][tid][1]; }
    float m = S * (1.0f / cC);
    float v = Q * (1.0f / cC) - m * m;
    meanL[tid] = m;
    invL[tid] = rsqrtf(v + 1e-5f);
  }
  __syncthreads();
  // ---- Phase 3: xln -> aT frag layout ONLY (cc keeps x; no global stash)
  #pragma unroll
  for (int nb = 0; nb < 2; ++nb) {
    int col = w * 32 + nb * 16 + lane15;
    float gc = g[col], bc = bt[col];
    int qd = nb * 2 + (lane15 >> 3);   // (col&31)>>3
    int jd = lane15 & 7;
    #pragma unroll
    for (int mf = 0; mf < 4; ++mf)
      #pragma unroll
      for (int i = 0; i < 4; ++i) {
        int rl = mf * 16 + kq * 4 + i;
        float lv = (cc[mf][nb][i] - meanL[rl]) * invL[rl] * gc + bc;
        aT[((mf * 8 + w) * 64 + qd * 16 + kq * 4 + i) * 8 + jd] = f2bf(lv);
      }
  }
  __syncthreads();                     // aT ready; meanL/invL dead (hL0 reusable)
  // ---- Phase 4: FFN loop, 8 chunks of 128 h-cols; h ping-pong hL0/hL1.
  // One barrier per chunk: GELU-write(c) to buf[c&1] is separated from
  // FFN2(c-2)'s reads of the same buf by barrier(c-1).
  #pragma unroll 1
  for (int hc2 = 0; hc2 < 8; ++hc2) {
    ushort_t* hB = (hc2 & 1) ? hL1 : hL0;
    // FFN1: wave w computes h cols [hc2*128 + w*16, +16)
    f32x4 c1[4];
    #pragma unroll
    for (int mf = 0; mf < 4; ++mf) c1[mf] = z;
    const int slot = hc2 * 8 + w;
    #pragma unroll 1
    for (int kc = 0; kc < 8; ++kc) {
      short8 a[4];
      #pragma unroll
      for (int mf = 0; mf < 4; ++mf)
        a[mf] = *(const short8*)&aT[((mf * 8 + kc) * 64 + lane) * 8];
      short8 b = *(const short8*)(w1s + (((size_t)kc * 64 + slot) * 64 + lane) * 8);
      #pragma unroll
      for (int mf = 0; mf < 4; ++mf)
        c1[mf] = __builtin_amdgcn_mfma_f32_16x16x32_bf16(a[mf], b, c1[mf], 0, 0, 0);
    }
    // GELU = x * sigmoid(2u) = x / (1 + e^(-2u))  [exact identity]
    {
      int k2g = hc2 * 128 + w * 16 + lane15;    // global h col
      float bias = b1[k2g];
      int kc2l = w >> 1;                        // local (k2&127)>>5
      int kq2 = (w * 2 + (lane15 >> 3)) & 3;    // local (k2>>3)&3
      int j2 = lane15 & 7;
      #pragma unroll
      for (int mf = 0; mf < 4; ++mf)
        #pragma unroll
        for (int i = 0; i < 4; ++i) {
          float xx = c1[mf][i] + bias;
          float x2v = xx * xx;
          float mm = fmaf(x2v, 0.044715f, 1.0f);
          float u2 = xx * mm * -1.5957691216057308f;   // -2*sqrt(2/pi)
          float e = __expf(u2);
          float ge = xx * __builtin_amdgcn_rcpf(1.0f + e);
          hB[((kc2l * 4 + mf) * 64 + kq2 * 16 + kq * 4 + i) * 8 + j2] = f2bf(ge);
        }
    }
    __syncthreads();                  // hB chunk ready
    // FFN2: K=128 (4 kc2), wave cols [w*32,+32), accumulate into cc (resid inside)
    #pragma unroll 1
    for (int kc2 = 0; kc2 < 4; ++kc2) {
      short8 a2[4];
      #pragma unroll
      for (int mf = 0; mf < 4; ++mf)
        a2[mf] = *(const short8*)&hB[((kc2 * 4 + mf) * 64 + lane) * 8];
      #pragma unroll
      for (int nb = 0; nb < 2; ++nb) {
        short8 b = *(const short8*)(w2s +
            (((size_t)(hc2 * 4 + kc2) * 16 + w * 2 + nb) * 64 + lane) * 8);
        #pragma unroll
        for (int mf = 0; mf < 4; ++mf)
          cc[mf][nb] = __builtin_amdgcn_mfma_f32_16x16x32_bf16(a2[mf], b, cc[mf][nb], 0, 0, 0);
      }
    }
  }
  __syncthreads();                     // all aT/hL frag reads complete
  // ---- Phase 5: cc (= x + FFN) + b2 -> aT row-major STRIDE 264
  #pragma unroll
  for (int nb = 0; nb < 2; ++nb) {
    int col = w * 32 + nb * 16 + lane15;
    float bias = b2[col];
    #pragma unroll
    for (int mf = 0; mf < 4; ++mf)
      #pragma unroll
      for (int i = 0; i < 4; ++i)
        aT[(mf * 16 + kq * 4 + i) * 264 + col] = f2bf(cc[mf][nb][i] + bias);
  }
  __syncthreads();
  // ---- gx-row x2 write (only rows the gx kernel reads: q%293==292)
  #pragma unroll
  for (int mf = 0; mf < 4; ++mf) {
    if ((rt0 + mf) % cHW == 292) {
      for (int f = tid; f < 1024; f += 512) {
        int rl = mf * 16 + (f >> 6), c4 = (f & 63) * 4;
        *(uint2*)&x2out[(size_t)(row0 + rl) * 256 + c4] = *(uint2*)&aT[rl * 264 + c4];
      }
    }
  }
  // ---- fused table/hand heads: waves 0-3 table (rows (w&3)*16), 4-7 hand
  {
    const int wl = w & 3;
    const bool isHand = (w >= 4);
    const ushort_t* Ws = isHand ? hws : tws;
    const float* Bi = isHand ? hb : tb;
    f32x4 ct[2];
    ct[0] = z; ct[1] = z;
    const ushort_t* arow = aT + (wl * 16 + lane15) * 264 + kq * 8;
    #pragma unroll
    for (int kc = 0; kc < 8; ++kc) {
      short8 a = *(const short8*)(arow + kc * 32);
      #pragma unroll
      for (int nb = 0; nb < 2; ++nb) {
        short8 bf_ = *(const short8*)(Ws + (((size_t)(kc * 2 + nb)) * 64 + lane) * 8);
        ct[nb] = __builtin_amdgcn_mfma_f32_16x16x32_bf16(a, bf_, ct[nb], 0, 0, 0);
      }
    }
    #pragma unroll
    for (int nb = 0; nb < 2; ++nb) {
      int j = nb * 16 + lane15;
      float bias = Bi[j];
      int uh = j >> 3, uw = (j >> 1) & 3, uc = j & 1;
      #pragma unroll
      for (int i = 0; i < 4; ++i) {
        int rg = row0 + wl * 16 + kq * 4 + i;
        int b = rg & 15, q = rg >> 4;
        int s = (q * 3579) >> 20;          // exact q/293 for q<14768
        int hw = q - s * cHW;
        if (!isHand && hw < 256) {
          int th = hw >> 4, twi = hw & 15;
          size_t idx = TX_OFF +
              ((((size_t)(s * cB + b)) * 2 + uc) * 64 + (th * 4 + uh)) * 64 + (twi * 4 + uw);
          out[idx] = ct[nb][i] + bias;
        } else if (isHand && hw >= 256 && hw < 292) {
          int h2 = hw - 256;
          int hh = h2 / 6, ww = h2 % 6;
          size_t idx = HX_OFF +
              ((((size_t)(s * cB + b)) * 2 + uc) * 24 + (hh * 4 + uh)) * 24 + (ww * 4 + uw);
          out[idx] = ct[nb][i] + bias;
        }
      }
    }
  }
}

// ============ MFMA attention: 512 threads, per (b,h), 16 q-tiles per block ============
__global__ __launch_bounds__(512, 4) void k_attn(
    const ushort_t* __restrict__ Qb, const ushort_t* __restrict__ Kb,
    const ushort_t* __restrict__ Vb, const int* __restrict__ tq,
    const int* __restrict__ tk, const int* __restrict__ pad_q,
    const int* __restrict__ pad_k, ushort_t* __restrict__ aout)
{
  __shared__ ushort_t KL[128 * 72];     // [k][d]
  __shared__ ushort_t VtL[64 * 136];    // [d][k]
  __shared__ ushort_t pL[8][16 * 136];  // per-wave P tile
  __shared__ int tkL[128];

  const int h = blockIdx.y, b = blockIdx.z;
  const int tid = threadIdx.x, lane = tid & 63, w = tid >> 6;   // w in [0,8)
  const int m15 = lane & 15, quad = lane >> 4;

  for (int i = tid; i < 128 * 16; i += 512) {
    int k = i >> 4, d4 = (i & 15) * 4;
    size_t src = (size_t)(k * cB + b) * 256 + h * 64 + d4;
    uint2 kv = *(const uint2*)&Kb[src];
    uint2 vv = *(const uint2*)&Vb[src];
    *(uint2*)&KL[k * 72 + d4] = kv;
    const ushort_t* vvp = (const ushort_t*)&vv;
    #pragma unroll
    for (int t = 0; t < 4; ++t) VtL[(d4 + t) * 136 + k] = vvp[t];
  }
  if (tid < 128) tkL[tid] = tk[tid * cB + b];
  __syncthreads();
  const int pk = pad_k[b];
  const int pq = pad_q[b] * cHW;
  ushort_t* pRow = pL[w];
  const f32x4 z = {0.f, 0.f, 0.f, 0.f};

  for (int pr = 0; pr < 2; ++pr) {
    int qt = blockIdx.x * 16 + pr * 8 + w;
    if (qt >= 293) break;                       // wave-uniform
    const ushort_t* qrow =
        Qb + ((size_t)((qt * 16 + m15) * cB + b)) * 256 + h * 64 + quad * 8;
    short8 qa0 = *(const short8*)(qrow);
    short8 qa1 = *(const short8*)(qrow + 32);
    f32x4 s[8];
    #pragma unroll
    for (int nf = 0; nf < 8; ++nf) {
      const ushort_t* kp = KL + (nf * 16 + m15) * 72 + quad * 8;
      short8 b0 = *(const short8*)(kp);
      short8 b1 = *(const short8*)(kp + 32);
      s[nf] = __builtin_amdgcn_mfma_f32_16x16x32_bf16(qa0, b0, z, 0, 0, 0);
      s[nf] = __builtin_amdgcn_mfma_f32_16x16x32_bf16(qa1, b1, s[nf], 0, 0, 0);
    }
    int tqv[4], qok[4];
    #pragma unroll
    for (int i = 0; i < 4; ++i) {
      int qg = qt * 16 + quad * 4 + i;
      int sidx = (qg * 3579) >> 20;            // exact q/293 for q<14768
      tqv[i] = tq[sidx * cB + b];
      qok[i] = (qg < pq);
    }
    #pragma unroll
    for (int nf = 0; nf < 8; ++nf) {
      int kidx = nf * 16 + m15;
      int tkc = tkL[kidx];
      bool kok = (kidx < pk);
      #pragma unroll
      for (int i = 0; i < 4; ++i) {
        bool ok = kok && qok[i] && (tkc <= tqv[i]);
        s[nf][i] = ok ? s[nf][i] * 0.125f : -1e9f;
      }
    }
    float mx[4], l[4];
    #pragma unroll
    for (int i = 0; i < 4; ++i) {
      float m = s[0][i];
      #pragma unroll
      for (int nf = 1; nf < 8; ++nf) m = fmaxf(m, s[nf][i]);
      #pragma unroll
      for (int off = 8; off >= 1; off >>= 1) m = fmaxf(m, __shfl_xor(m, off, 64));
      mx[i] = m;
    }
    #pragma unroll
    for (int i = 0; i < 4; ++i) l[i] = 0.f;
    #pragma unroll
    for (int nf = 0; nf < 8; ++nf)
      #pragma unroll
      for (int i = 0; i < 4; ++i) {
        float p = __expf(s[nf][i] - mx[i]);
        s[nf][i] = p;
        l[i] += p;
      }
    #pragma unroll
    for (int i = 0; i < 4; ++i) {
      float t = l[i];
      #pragma unroll
      for (int off = 8; off >= 1; off >>= 1) t += __shfl_xor(t, off, 64);
      l[i] = 1.0f / t;
    }
    #pragma unroll
    for (int nf = 0; nf < 8; ++nf)
      #pragma unroll
      for (int i = 0; i < 4; ++i)
        pRow[(quad * 4 + i) * 136 + nf * 16 + m15] = f2bf(s[nf][i]);
    f32x4 o[4];
    #pragma unroll
    for (int nf = 0; nf < 4; ++nf) o[nf] = z;
    #pragma unroll
    for (int kc = 0; kc < 4; ++kc) {
      short8 pa = *(const short8*)(pRow + m15 * 136 + kc * 32 + quad * 8);
      #pragma unroll
      for (int nf = 0; nf < 4; ++nf) {
        short8 vb = *(const short8*)(VtL + (nf * 16 + m15) * 136 + kc * 32 + quad * 8);
        o[nf] = __builtin_amdgcn_mfma_f32_16x16x32_bf16(pa, vb, o[nf], 0, 0, 0);
      }
    }
    #pragma unroll
    for (int nf = 0; nf < 4; ++nf) {
      int c = h * 64 + nf * 16 + m15;
      size_t base = ((size_t)(c >> 5)) * 64 + ((c >> 3) & 3) * 16 + b;
      int cj = c & 7;
      #pragma unroll
      for (int i = 0; i < 4; ++i) {
        int qg = qt * 16 + quad * 4 + i;
        aout[(((size_t)qg * 8) * 64 + base) * 8 + cj] = f2bf(o[nf][i] * l[i]);
      }
    }
  }
}

// ============ gx heads only (table/hand heads fused into k_woffn) ============
__global__ __launch_bounds__(256, 4) void k_thg(
    const ushort_t* __restrict__ x2,
    const float* __restrict__ mw, const float* __restrict__ mbi,
    const float* __restrict__ sw, const float* __restrict__ sbi,
    const float* __restrict__ cw, const float* __restrict__ cbi,
    float* __restrict__ out)
{
  __shared__ float rowL[256];
  const int tid = threadIdx.x;
  int sb = blockIdx.x;                 // s*16 + b
  int s = sb >> 4, b = sb & 15;
  const ushort_t* row = x2 + ((size_t)(s * cHW + 292) * cB + b) * cC;
  rowL[tid] = bf2f(row[tid]);
  __syncthreads();
  int j = tid;
  if (j < 100) {
    const float* W;
    const float* Bi;
    int jj, M;
    size_t off;
    if (j < 20)      { W = mw; Bi = mbi; jj = j;      M = 20; off = 0;     }
    else if (j < 84) { W = sw; Bi = sbi; jj = j - 20; M = 64; off = 5120;  }
    else             { W = cw; Bi = cbi; jj = j - 84; M = 16; off = 21504; }
    float acc = Bi[jj];
    for (int c = 0; c < 256; ++c) acc = fmaf(rowL[c], W[c * M + jj], acc);
    out[off + (size_t)sb * M + jj] = acc;
  }
}

extern "C" void kernel_launch(void* const* d_in, const int* in_sizes, int n_in,
                              void* d_out, int out_size, void* d_ws, size_t ws_size,
                              hipStream_t stream)
{
  const int*   tq       = (const int*)d_in[0];
  const int*   pad_q    = (const int*)d_in[1];
  const float* xk       = (const float*)d_in[2];
  const int*   tk       = (const int*)d_in[3];
  const int*   pad_k    = (const int*)d_in[4];
  const float* spatial  = (const float*)d_in[8];
  const float* temporal = (const float*)d_in[9];
  const float* ln1_g    = (const float*)d_in[10];
  const float* ln1_b    = (const float*)d_in[11];
  const float* wq       = (const float*)d_in[12];
  const float* bq       = (const float*)d_in[13];
  const float* wk       = (const float*)d_in[14];
  const float* bk       = (const float*)d_in[15];
  const float* wv       = (const float*)d_in[16];
  const float* bv       = (const float*)d_in[17];
  const float* wo       = (const float*)d_in[18];
  const float* bo       = (const float*)d_in[19];
  const float* ln2_g    = (const float*)d_in[20];
  const float* ln2_b    = (const float*)d_in[21];
  const float* w1       = (const float*)d_in[22];
  const float* b1       = (const float*)d_in[23];
  const float* w2       = (const float*)d_in[24];
  const float* b2       = (const float*)d_in[25];
  const float* table_w  = (const float*)d_in[26];
  const float* table_b  = (const float*)d_in[27];
  const float* hand_w   = (const float*)d_in[28];
  const float* hand_b   = (const float*)d_in[29];
  const float* mode_w   = (const float*)d_in[30];
  const float* mode_b   = (const float*)d_in[31];
  const float* shape_w  = (const float*)d_in[32];
  const float* shape_b  = (const float*)d_in[33];
  const float* color_w  = (const float*)d_in[34];
  const float* color_b  = (const float*)d_in[35];
  float* out = (float*)d_out;

  char* ws = (char*)d_ws;
  const size_t NB2 = (size_t)cNN * cC * sizeof(ushort_t);      // 38,404,096
  ushort_t* buf1 = (ushort_t*)ws;                              // a_swz (attn out)
  ushort_t* buf2 = (ushort_t*)(ws + NB2);                      // Q -> x2 (gx rows)
  char* p = ws + 2 * NB2;
  ushort_t* Kb  = (ushort_t*)p;  p += (size_t)cLK * cB * 256 * 2;
  ushort_t* Vb  = (ushort_t*)p;  p += (size_t)cLK * cB * 256 * 2;
  ushort_t* xkb = (ushort_t*)p;  p += (size_t)cLK * cB * 256 * 2;
  ushort_t* wqs = (ushort_t*)p;  p += 256 * 256 * 2;
  ushort_t* wks = (ushort_t*)p;  p += 256 * 256 * 2;
  ushort_t* wvs = (ushort_t*)p;  p += 256 * 256 * 2;
  ushort_t* wos = (ushort_t*)p;  p += 256 * 256 * 2;
  ushort_t* w1s = (ushort_t*)p;  p += 256 * 1024 * 2;
  ushort_t* w2s = (ushort_t*)p;  p += 1024 * 256 * 2;
  ushort_t* tws = (ushort_t*)p;  p += 256 * 32 * 2;
  ushort_t* hws = (ushort_t*)p;  p += 256 * 32 * 2;

  k_prep<<<904, 256, 0, stream>>>(xk, xkb, wq, wqs, wk, wks, wv, wvs,
                                  wo, wos, w1, w1s, w2, w2s,
                                  table_w, tws, hand_w, hws);
  k_qnpkv<<<cNN / 64 + 64, 256, 0, stream>>>(tq, spatial, temporal, ln1_g, ln1_b,
                                             wqs, bq, buf2, xkb, wks, wvs,
                                             bk, bv, Kb, Vb);
  k_attn<<<dim3(19, cH, cB), 512, 0, stream>>>(buf2, Kb, Vb, tq, tk,
                                               pad_q, pad_k, buf1);
  k_woffn<<<cNN / 64, 512, 0, stream>>>(buf1, wos, bo, tq, spatial, temporal,
                                        ln2_g, ln2_b, w1s, b1, w2s, b2, buf2,
                                        tws, table_b, hws, hand_b, out);
  k_thg<<<cS * cB, 256, 0, stream>>>(buf2, mode_w, mode_b, shape_w, shape_b,
                                     color_w, color_b, out);
}

// Round 13
// 372.503 us; speedup vs baseline: 1.0677x; 1.0100x over previous
//
#include <hip/hip_runtime.h>
#include <hip/hip_bf16.h>

namespace {
constexpr int cS = 16, cB = 16, cC = 256, cH = 4, cDH = 64, cHW = 293;
constexpr int cLQ = cS * cHW;      // 4688
constexpr int cLK = 128;
constexpr int cNN = cLQ * cB;      // 75008
constexpr size_t TX_OFF = 25600;         // 5120 + 16384 + 4096
constexpr size_t HX_OFF = 2122752;       // TX_OFF + 16*16*2*64*64
}

typedef unsigned short ushort_t;
typedef unsigned int uint_t;
typedef __attribute__((ext_vector_type(8))) short short8;    // 8 bf16 (4 VGPRs)
typedef __attribute__((ext_vector_type(4))) float f32x4;     // MFMA C/D frag

__device__ __forceinline__ float bf2f(ushort_t u) {
  return __uint_as_float(((uint_t)u) << 16);
}
__device__ __forceinline__ ushort_t f2bf(float f) {
  __hip_bfloat16 h = __float2bfloat16(f);
  return *(ushort_t*)&h;
}

// SWZ frag-linear activation layout for a [rows][256] matrix:
// element (r, c) -> ((r>>4)*8 + (c>>5))*512 + ((c>>3)&3)*128 + (r&15)*8 + (c&7)
__device__ __forceinline__ size_t swz(int r, int c) {
  return (((size_t)(r >> 4) * 8 + (c >> 5)) * 64 + ((c >> 3) & 3) * 16 + (r & 15)) * 8 + (c & 7);
}

// ============ merged prep: xk cvt+swz, 8 weight swizzles ============
__global__ __launch_bounds__(256) void k_prep(
    const float* __restrict__ xk, ushort_t* __restrict__ xkb,
    const float* __restrict__ wq, ushort_t* __restrict__ wqs,
    const float* __restrict__ wk, ushort_t* __restrict__ wks,
    const float* __restrict__ wv, ushort_t* __restrict__ wvs,
    const float* __restrict__ wo, ushort_t* __restrict__ wos,
    const float* __restrict__ w1, ushort_t* __restrict__ w1s,
    const float* __restrict__ w2, ushort_t* __restrict__ w2s,
    const float* __restrict__ tw, ushort_t* __restrict__ tws,
    const float* __restrict__ hw_, ushort_t* __restrict__ hws)
{
  int bid = blockIdx.x;
  if (bid < 512) {
    int i4 = bid * 256 + threadIdx.x;
    int r = i4 >> 6;
    int c0 = (i4 & 63) * 4;
    float4 v = *(const float4*)(xk + (size_t)r * 256 + c0);
    ushort_t o[4] = {f2bf(v.x), f2bf(v.y), f2bf(v.z), f2bf(v.w)};
    *(uint2*)&xkb[swz(r, c0)] = *(uint2*)o;
    return;
  }
  int rr = bid - 512;
  const float* W; ushort_t* Ws; int N; int lb;
  if      (rr < 32)  { W = wq;  Ws = wqs; N = 256;  lb = rr; }
  else if (rr < 64)  { W = wk;  Ws = wks; N = 256;  lb = rr - 32; }
  else if (rr < 96)  { W = wv;  Ws = wvs; N = 256;  lb = rr - 64; }
  else if (rr < 128) { W = wo;  Ws = wos; N = 256;  lb = rr - 96; }
  else if (rr < 256) { W = w1;  Ws = w1s; N = 1024; lb = rr - 128; }
  else if (rr < 384) { W = w2;  Ws = w2s; N = 256;  lb = rr - 256; }
  else if (rr < 388) { W = tw;  Ws = tws; N = 32;   lb = rr - 384; }
  else               { W = hw_; Ws = hws; N = 32;   lb = rr - 388; }
  int slot = lb * 256 + threadIdx.x;
  int lane = slot & 63;
  int fr   = slot >> 6;
  int NB   = N >> 4;
  int nb   = fr % NB, kc = fr / NB;
  int n    = nb * 16 + (lane & 15);
  int k0   = kc * 32 + (lane >> 4) * 8;
  ushort_t tmp[8];
  #pragma unroll
  for (int i = 0; i < 8; ++i) tmp[i] = f2bf(W[(size_t)(k0 + i) * N + n]);
  *(uint4*)&Ws[(size_t)slot * 8] = *(uint4*)tmp;
}

// ============ core GEMM: 64 rows x (4x16 cols/wave), K=256, N-split waves ============
__device__ __forceinline__ void gemm_k256(
    const ushort_t* __restrict__ A, const ushort_t* __restrict__ Ws,
    int rt0, int slot0, int NB, int lane, f32x4 c[4][4])
{
  #pragma unroll 2
  for (int kc = 0; kc < 8; ++kc) {
    short8 a[4];
    #pragma unroll
    for (int mf = 0; mf < 4; ++mf)
      a[mf] = *(const short8*)(A + (((size_t)(rt0 + mf) * 8 + kc) * 64 + lane) * 8);
    #pragma unroll
    for (int nb = 0; nb < 4; ++nb) {
      short8 b = *(const short8*)(Ws + (((size_t)kc * NB + slot0 + nb) * 64 + lane) * 8);
      #pragma unroll
      for (int mf = 0; mf < 4; ++mf)
        c[mf][nb] = __builtin_amdgcn_mfma_f32_16x16x32_bf16(a[mf], b, c[mf][nb], 0, 0, 0);
    }
  }
}

// ============ merged: fused xq+LN1+Q-projection (bid<1172) OR K/V proj (bid>=1172) ====
// R13: LN1 restructured — 4 quads x 16 lanes; each quad owns one row per pass
// (lane covers 16 channels), so the row reduction is a 4-step shfl within 16
// lanes and 4 rows proceed in parallel. Cross-lane dependency chain 96 -> 16
// steps vs the old 16x serial full-wave reduction.
__global__ __launch_bounds__(256, 4) void k_qnpkv(
    const int* __restrict__ tq, const float* __restrict__ spatial,
    const float* __restrict__ temporal, const float* __restrict__ g,
    const float* __restrict__ bt, const ushort_t* __restrict__ wqs,
    const float* __restrict__ bq, ushort_t* __restrict__ Out,
    const ushort_t* __restrict__ xkb, const ushort_t* __restrict__ wks,
    const ushort_t* __restrict__ wvs, const float* __restrict__ bk,
    const float* __restrict__ bv, ushort_t* __restrict__ Kb,
    ushort_t* __restrict__ Vb)
{
  __shared__ ushort_t aT[64 * 256];    // A frags, then reused as epilogue tile
  const int NQ = cNN / 64;             // 1172
  const int tid = threadIdx.x, lane = tid & 63, w = tid >> 6;
  const int lane15 = lane & 15, kq = lane >> 4;
  f32x4 z = {0.f, 0.f, 0.f, 0.f};

  if ((int)blockIdx.x >= NQ) {
    // ---- K/V projection path
    int bid2 = blockIdx.x - NQ;        // 0..63
    const ushort_t* Ws = (bid2 >> 5) ? wvs : wks;
    const float* Bi = (bid2 >> 5) ? bv : bk;
    ushort_t* Kv = (bid2 >> 5) ? Vb : Kb;
    const int bx = bid2 & 31;
    const int rt0 = bx * 4, row0 = bx * 64;
    f32x4 c[4][4];
    #pragma unroll
    for (int mf = 0; mf < 4; ++mf)
      #pragma unroll
      for (int nb = 0; nb < 4; ++nb) c[mf][nb] = z;
    gemm_k256(xkb, Ws, rt0, w * 4, 16, lane, c);
    #pragma unroll
    for (int nb = 0; nb < 4; ++nb) {
      int col = w * 64 + nb * 16 + lane15;
      float bias = Bi[col];
      #pragma unroll
      for (int mf = 0; mf < 4; ++mf)
        #pragma unroll
        for (int i = 0; i < 4; ++i) {
          int row = row0 + mf * 16 + kq * 4 + i;
          Kv[(size_t)row * 256 + col] = f2bf(c[mf][nb][i] + bias);
        }
    }
    return;
  }

  // ---- xq + LN1 + Q-projection path
  const int rt0 = blockIdx.x * 4, row0 = blockIdx.x * 64;
  {
    int q = rt0 + w;                   // wave-uniform
    int s = q / cHW, hw = q % cHW;
    const int quad4 = lane >> 4;       // row within group of 4
    #pragma unroll 1
    for (int rrg = 0; rrg < 4; ++rrg) {
      int rr = rrg * 4 + quad4;
      int t = tq[s * cB + rr];
      float4 v[4];
      float sum = 0.f, sum2 = 0.f;
      #pragma unroll
      for (int ch = 0; ch < 4; ++ch) {
        int c0 = ch * 64 + lane15 * 4;
        float4 tv = *(const float4*)(temporal + (size_t)t * cC + c0);
        float4 sv = *(const float4*)(spatial + (size_t)hw * cC + c0);
        float4 vv;
        vv.x = tv.x + sv.x; vv.y = tv.y + sv.y;
        vv.z = tv.z + sv.z; vv.w = tv.w + sv.w;
        v[ch] = vv;
        sum  += vv.x + vv.y + vv.z + vv.w;
        sum2 += vv.x * vv.x + vv.y * vv.y + vv.z * vv.z + vv.w * vv.w;
      }
      #pragma unroll
      for (int off = 8; off >= 1; off >>= 1) {
        sum  += __shfl_xor(sum,  off, 64);
        sum2 += __shfl_xor(sum2, off, 64);
      }
      float mean = sum * (1.0f / cC);
      float var  = sum2 * (1.0f / cC) - mean * mean;
      float inv  = rsqrtf(var + 1e-5f);
      #pragma unroll
      for (int ch = 0; ch < 4; ++ch) {
        int c0 = ch * 64 + lane15 * 4;
        float4 g4 = *(const float4*)(g + c0);
        float4 b4 = *(const float4*)(bt + c0);
        int kc = c0 >> 5, qq = (c0 >> 3) & 3, joff = c0 & 7;
        ushort_t o[4] = {f2bf((v[ch].x - mean) * inv * g4.x + b4.x),
                         f2bf((v[ch].y - mean) * inv * g4.y + b4.y),
                         f2bf((v[ch].z - mean) * inv * g4.z + b4.z),
                         f2bf((v[ch].w - mean) * inv * g4.w + b4.w)};
        *(uint2*)&aT[(((w * 8 + kc) * 64) + qq * 16 + rr) * 8 + joff] = *(uint2*)o;
      }
    }
  }
  __syncthreads();
  f32x4 c[4][4];
  #pragma unroll
  for (int mf = 0; mf < 4; ++mf)
    #pragma unroll
    for (int nb = 0; nb < 4; ++nb) c[mf][nb] = z;
  gemm_k256(aT, wqs, 0, w * 4, 16, lane, c);
  __syncthreads();                     // all aT frag reads complete
  #pragma unroll
  for (int nb = 0; nb < 4; ++nb) {
    int col = w * 64 + nb * 16 + lane15;
    float bias = bq[col];
    #pragma unroll
    for (int mf = 0; mf < 4; ++mf)
      #pragma unroll
      for (int i = 0; i < 4; ++i)
        aT[(mf * 16 + kq * 4 + i) * 256 + col] = f2bf(c[mf][nb][i] + bias);
  }
  __syncthreads();
  uint2* outp = (uint2*)(Out + (size_t)row0 * 256);
  #pragma unroll
  for (int it = 0; it < 16; ++it) {
    int f = tid + it * 256;
    int row = f >> 6, c0 = (f & 63) * 4;
    outp[f] = *(uint2*)&aT[row * 256 + c0];
  }
}

// ============ MEGA-FUSED: wo proj + xq resid + LN2 + FFN1 + GELU + FFN2 + resid
//              + table/hand heads (fused from k_thg) ====
// R10 configuration (verified 376us total, k_woffn 181us). Do not deepen
// per-block pipelining here (R2/R11: costs 2-block co-residency).
__global__ __launch_bounds__(512, 8) void k_woffn(
    const ushort_t* __restrict__ A, const ushort_t* __restrict__ wos,
    const float* __restrict__ bo, const int* __restrict__ tq,
    const float* __restrict__ spatial, const float* __restrict__ temporal,
    const float* __restrict__ g, const float* __restrict__ bt,
    const ushort_t* __restrict__ w1s, const float* __restrict__ b1,
    const ushort_t* __restrict__ w2s, const float* __restrict__ b2,
    ushort_t* __restrict__ x2out,
    const ushort_t* __restrict__ tws, const float* __restrict__ tb,
    const ushort_t* __restrict__ hws, const float* __restrict__ hb,
    float* __restrict__ out)
{
  __shared__ ushort_t aT[64 * 264];     // frag use: first 16384 elems; epilogue stride 264
  __shared__ ushort_t hL0[64 * 128];    // h ping buffer (16KB); LN2 scratch aliased
  __shared__ ushort_t hL1[64 * 128];    // h pong buffer (16KB)
  float (*red)[64][2] = (float (*)[64][2])hL0;       // 8*64*2*4 = 4096 B
  float* meanL = (float*)hL0 + 1024;                 // +4096 B
  float* invL  = meanL + 64;                         // ends < 16384
  const int tid = threadIdx.x, lane = tid & 63, w = tid >> 6;   // w in [0,8)
  const int lane15 = lane & 15, kq = lane >> 4;
  const int rt0 = blockIdx.x * 4, row0 = blockIdx.x * 64;
  const f32x4 z = {0.f, 0.f, 0.f, 0.f};

  // ---- Phase 1: wo GEMM, cc[4][2] over wave's 32 cols
  f32x4 cc[4][2];   // wo-GEMM -> residual carrier -> FFN2 accumulates ON TOP
  #pragma unroll
  for (int mf = 0; mf < 4; ++mf)
    #pragma unroll
    for (int nb = 0; nb < 2; ++nb) cc[mf][nb] = z;
  #pragma unroll 1
  for (int kc = 0; kc < 8; ++kc) {
    short8 a[4];
    #pragma unroll
    for (int mf = 0; mf < 4; ++mf)
      a[mf] = *(const short8*)(A + (((size_t)(rt0 + mf) * 8 + kc) * 64 + lane) * 8);
    #pragma unroll
    for (int nb = 0; nb < 2; ++nb) {
      short8 b = *(const short8*)(wos + (((size_t)kc * 16 + w * 2 + nb) * 64 + lane) * 8);
      #pragma unroll
      for (int mf = 0; mf < 4; ++mf)
        cc[mf][nb] = __builtin_amdgcn_mfma_f32_16x16x32_bf16(a[mf], b, cc[mf][nb], 0, 0, 0);
    }
  }
  // ---- + bias + xq (recomputed): cc now holds the residual x in f32
  {
    int tt[4][4], hws_[4];
    #pragma unroll
    for (int mf = 0; mf < 4; ++mf) {
      int q = rt0 + mf;
      int s = q / cHW;
      hws_[mf] = q % cHW;
      #pragma unroll
      for (int i = 0; i < 4; ++i) tt[mf][i] = tq[s * cB + kq * 4 + i];
    }
    #pragma unroll
    for (int nb = 0; nb < 2; ++nb) {
      int col = w * 32 + nb * 16 + lane15;
      float bias = bo[col];
      #pragma unroll
      for (int mf = 0; mf < 4; ++mf) {
        float sp = spatial[(size_t)hws_[mf] * cC + col];
        #pragma unroll
        for (int i = 0; i < 4; ++i)
          cc[mf][nb][i] += bias + temporal[(size_t)tt[mf][i] * cC + col] + sp;
      }
    }
  }
  // ---- Phase 2: LN2 stats (cross-wave; scratch lives in hL0 alias)
  #pragma unroll
  for (int mf = 0; mf < 4; ++mf)
    #pragma unroll
    for (int i = 0; i < 4; ++i) {
      float s4 = cc[mf][0][i] + cc[mf][1][i];
      float q4 = cc[mf][0][i] * cc[mf][0][i] + cc[mf][1][i] * cc[mf][1][i];
      #pragma unroll
      for (int off = 8; off >= 1; off >>= 1) {
        s4 += __shfl_xor(s4, off, 64);
        q4 += __shfl_xor(q4, off, 64);
      }
      if (lane15 == 0) {
        red[w][mf * 16 + kq * 4 + i][0] = s4;
        red[w][mf * 16 + kq * 4 + i][1] = q4;
      }
    }
  __syncthreads();
  if (tid < 64) {
    float S = 0.f, Q = 0.f;
    #pragma unroll
    for (int ww = 0; ww < 8; ++ww) { S += red[ww][tid][0]; Q += red[ww][tid][1]; }
    float m = S * (1.0f / cC);
    float v = Q * (1.0f / cC) - m * m;
    meanL[tid] = m;
    invL[tid] = rsqrtf(v + 1e-5f);
  }
  __syncthreads();
  // ---- Phase 3: xln -> aT frag layout ONLY (cc keeps x; no global stash)
  #pragma unroll
  for (int nb = 0; nb < 2; ++nb) {
    int col = w * 32 + nb * 16 + lane15;
    float gc = g[col], bc = bt[col];
    int qd = nb * 2 + (lane15 >> 3);   // (col&31)>>3
    int jd = lane15 & 7;
    #pragma unroll
    for (int mf = 0; mf < 4; ++mf)
      #pragma unroll
      for (int i = 0; i < 4; ++i) {
        int rl = mf * 16 + kq * 4 + i;
        float lv = (cc[mf][nb][i] - meanL[rl]) * invL[rl] * gc + bc;
        aT[((mf * 8 + w) * 64 + qd * 16 + kq * 4 + i) * 8 + jd] = f2bf(lv);
      }
  }
  __syncthreads();                     // aT ready; meanL/invL dead (hL0 reusable)
  // ---- Phase 4: FFN loop, 8 chunks of 128 h-cols; h ping-pong hL0/hL1.
  // One barrier per chunk: GELU-write(c) to buf[c&1] is separated from
  // FFN2(c-2)'s reads of the same buf by barrier(c-1).
  #pragma unroll 1
  for (int hc2 = 0; hc2 < 8; ++hc2) {
    ushort_t* hB = (hc2 & 1) ? hL1 : hL0;
    // FFN1: wave w computes h cols [hc2*128 + w*16, +16)
    f32x4 c1[4];
    #pragma unroll
    for (int mf = 0; mf < 4; ++mf) c1[mf] = z;
    const int slot = hc2 * 8 + w;
    #pragma unroll 1
    for (int kc = 0; kc < 8; ++kc) {
      short8 a[4];
      #pragma unroll
      for (int mf = 0; mf < 4; ++mf)
        a[mf] = *(const short8*)&aT[((mf * 8 + kc) * 64 + lane) * 8];
      short8 b = *(const short8*)(w1s + (((size_t)kc * 64 + slot) * 64 + lane) * 8);
      #pragma unroll
      for (int mf = 0; mf < 4; ++mf)
        c1[mf] = __builtin_amdgcn_mfma_f32_16x16x32_bf16(a[mf], b, c1[mf], 0, 0, 0);
    }
    // GELU = x * sigmoid(2u) = x / (1 + e^(-2u))  [exact identity]
    {
      int k2g = hc2 * 128 + w * 16 + lane15;    // global h col
      float bias = b1[k2g];
      int kc2l = w >> 1;                        // local (k2&127)>>5
      int kq2 = (w * 2 + (lane15 >> 3)) & 3;    // local (k2>>3)&3
      int j2 = lane15 & 7;
      #pragma unroll
      for (int mf = 0; mf < 4; ++mf)
        #pragma unroll
        for (int i = 0; i < 4; ++i) {
          float xx = c1[mf][i] + bias;
          float x2v = xx * xx;
          float mm = fmaf(x2v, 0.044715f, 1.0f);
          float u2 = xx * mm * -1.5957691216057308f;   // -2*sqrt(2/pi)
          float e = __expf(u2);
          float ge = xx * __builtin_amdgcn_rcpf(1.0f + e);
          hB[((kc2l * 4 + mf) * 64 + kq2 * 16 + kq * 4 + i) * 8 + j2] = f2bf(ge);
        }
    }
    __syncthreads();                  // hB chunk ready
    // FFN2: K=128 (4 kc2), wave cols [w*32,+32), accumulate into cc (resid inside)
    #pragma unroll 1
    for (int kc2 = 0; kc2 < 4; ++kc2) {
      short8 a2[4];
      #pragma unroll
      for (int mf = 0; mf < 4; ++mf)
        a2[mf] = *(const short8*)&hB[((kc2 * 4 + mf) * 64 + lane) * 8];
      #pragma unroll
      for (int nb = 0; nb < 2; ++nb) {
        short8 b = *(const short8*)(w2s +
            (((size_t)(hc2 * 4 + kc2) * 16 + w * 2 + nb) * 64 + lane) * 8);
        #pragma unroll
        for (int mf = 0; mf < 4; ++mf)
          cc[mf][nb] = __builtin_amdgcn_mfma_f32_16x16x32_bf16(a2[mf], b, cc[mf][nb], 0, 0, 0);
      }
    }
  }
  __syncthreads();                     // all aT/hL frag reads complete
  // ---- Phase 5: cc (= x + FFN) + b2 -> aT row-major STRIDE 264
  #pragma unroll
  for (int nb = 0; nb < 2; ++nb) {
    int col = w * 32 + nb * 16 + lane15;
    float bias = b2[col];
    #pragma unroll
    for (int mf = 0; mf < 4; ++mf)
      #pragma unroll
      for (int i = 0; i < 4; ++i)
        aT[(mf * 16 + kq * 4 + i) * 264 + col] = f2bf(cc[mf][nb][i] + bias);
  }
  __syncthreads();
  // ---- gx-row x2 write (only rows the gx kernel reads: q%293==292)
  #pragma unroll
  for (int mf = 0; mf < 4; ++mf) {
    if ((rt0 + mf) % cHW == 292) {
      for (int f = tid; f < 1024; f += 512) {
        int rl = mf * 16 + (f >> 6), c4 = (f & 63) * 4;
        *(uint2*)&x2out[(size_t)(row0 + rl) * 256 + c4] = *(uint2*)&aT[rl * 264 + c4];
      }
    }
  }
  // ---- fused table/hand heads: waves 0-3 table (rows (w&3)*16), 4-7 hand
  {
    const int wl = w & 3;
    const bool isHand = (w >= 4);
    const ushort_t* Ws = isHand ? hws : tws;
    const float* Bi = isHand ? hb : tb;
    f32x4 ct[2];
    ct[0] = z; ct[1] = z;
    const ushort_t* arow = aT + (wl * 16 + lane15) * 264 + kq * 8;
    #pragma unroll
    for (int kc = 0; kc < 8; ++kc) {
      short8 a = *(const short8*)(arow + kc * 32);
      #pragma unroll
      for (int nb = 0; nb < 2; ++nb) {
        short8 bf_ = *(const short8*)(Ws + (((size_t)(kc * 2 + nb)) * 64 + lane) * 8);
        ct[nb] = __builtin_amdgcn_mfma_f32_16x16x32_bf16(a, bf_, ct[nb], 0, 0, 0);
      }
    }
    #pragma unroll
    for (int nb = 0; nb < 2; ++nb) {
      int j = nb * 16 + lane15;
      float bias = Bi[j];
      int uh = j >> 3, uw = (j >> 1) & 3, uc = j & 1;
      #pragma unroll
      for (int i = 0; i < 4; ++i) {
        int rg = row0 + wl * 16 + kq * 4 + i;
        int b = rg & 15, q = rg >> 4;
        int s = (q * 3579) >> 20;          // exact q/293 for q<14768
        int hw = q - s * cHW;
        if (!isHand && hw < 256) {
          int th = hw >> 4, twi = hw & 15;
          size_t idx = TX_OFF +
              ((((size_t)(s * cB + b)) * 2 + uc) * 64 + (th * 4 + uh)) * 64 + (twi * 4 + uw);
          out[idx] = ct[nb][i] + bias;
        } else if (isHand && hw >= 256 && hw < 292) {
          int h2 = hw - 256;
          int hh = h2 / 6, ww = h2 % 6;
          size_t idx = HX_OFF +
              ((((size_t)(s * cB + b)) * 2 + uc) * 24 + (hh * 4 + uh)) * 24 + (ww * 4 + uw);
          out[idx] = ct[nb][i] + bias;
        }
      }
    }
  }
}

// ============ MFMA attention: 512 threads, per (b,h), 16 q-tiles per block ============
__global__ __launch_bounds__(512, 4) void k_attn(
    const ushort_t* __restrict__ Qb, const ushort_t* __restrict__ Kb,
    const ushort_t* __restrict__ Vb, const int* __restrict__ tq,
    const int* __restrict__ tk, const int* __restrict__ pad_q,
    const int* __restrict__ pad_k, ushort_t* __restrict__ aout)
{
  __shared__ ushort_t KL[128 * 72];     // [k][d]
  __shared__ ushort_t VtL[64 * 136];    // [d][k]
  __shared__ ushort_t pL[8][16 * 136];  // per-wave P tile
  __shared__ int tkL[128];

  const int h = blockIdx.y, b = blockIdx.z;
  const int tid = threadIdx.x, lane = tid & 63, w = tid >> 6;   // w in [0,8)
  const int m15 = lane & 15, quad = lane >> 4;

  for (int i = tid; i < 128 * 16; i += 512) {
    int k = i >> 4, d4 = (i & 15) * 4;
    size_t src = (size_t)(k * cB + b) * 256 + h * 64 + d4;
    uint2 kv = *(const uint2*)&Kb[src];
    uint2 vv = *(const uint2*)&Vb[src];
    *(uint2*)&KL[k * 72 + d4] = kv;
    const ushort_t* vvp = (const ushort_t*)&vv;
    #pragma unroll
    for (int t = 0; t < 4; ++t) VtL[(d4 + t) * 136 + k] = vvp[t];
  }
  if (tid < 128) tkL[tid] = tk[tid * cB + b];
  __syncthreads();
  const int pk = pad_k[b];
  const int pq = pad_q[b] * cHW;
  ushort_t* pRow = pL[w];
  const f32x4 z = {0.f, 0.f, 0.f, 0.f};

  for (int pr = 0; pr < 2; ++pr) {
    int qt = blockIdx.x * 16 + pr * 8 + w;
    if (qt >= 293) break;                       // wave-uniform
    const ushort_t* qrow =
        Qb + ((size_t)((qt * 16 + m15) * cB + b)) * 256 + h * 64 + quad * 8;
    short8 qa0 = *(const short8*)(qrow);
    short8 qa1 = *(const short8*)(qrow + 32);
    f32x4 s[8];
    #pragma unroll
    for (int nf = 0; nf < 8; ++nf) {
      const ushort_t* kp = KL + (nf * 16 + m15) * 72 + quad * 8;
      short8 b0 = *(const short8*)(kp);
      short8 b1 = *(const short8*)(kp + 32);
      s[nf] = __builtin_amdgcn_mfma_f32_16x16x32_bf16(qa0, b0, z, 0, 0, 0);
      s[nf] = __builtin_amdgcn_mfma_f32_16x16x32_bf16(qa1, b1, s[nf], 0, 0, 0);
    }
    int tqv[4], qok[4];
    #pragma unroll
    for (int i = 0; i < 4; ++i) {
      int qg = qt * 16 + quad * 4 + i;
      int sidx = (qg * 3579) >> 20;            // exact q/293 for q<14768
      tqv[i] = tq[sidx * cB + b];
      qok[i] = (qg < pq);
    }
    #pragma unroll
    for (int nf = 0; nf < 8; ++nf) {
      int kidx = nf * 16 + m15;
      int tkc = tkL[kidx];
      bool kok = (kidx < pk);
      #pragma unroll
      for (int i = 0; i < 4; ++i) {
        bool ok = kok && qok[i] && (tkc <= tqv[i]);
        s[nf][i] = ok ? s[nf][i] * 0.125f : -1e9f;
      }
    }
    float mx[4], l[4];
    #pragma unroll
    for (int i = 0; i < 4; ++i) {
      float m = s[0][i];
      #pragma unroll
      for (int nf = 1; nf < 8; ++nf) m = fmaxf(m, s[nf][i]);
      #pragma unroll
      for (int off = 8; off >= 1; off >>= 1) m = fmaxf(m, __shfl_xor(m, off, 64));
      mx[i] = m;
    }
    #pragma unroll
    for (int i = 0; i < 4; ++i) l[i] = 0.f;
    #pragma unroll
    for (int nf = 0; nf < 8; ++nf)
      #pragma unroll
      for (int i = 0; i < 4; ++i) {
        float p = __expf(s[nf][i] - mx[i]);
        s[nf][i] = p;
        l[i] += p;
      }
    #pragma unroll
    for (int i = 0; i < 4; ++i) {
      float t = l[i];
      #pragma unroll
      for (int off = 8; off >= 1; off >>= 1) t += __shfl_xor(t, off, 64);
      l[i] = 1.0f / t;
    }
    #pragma unroll
    for (int nf = 0; nf < 8; ++nf)
      #pragma unroll
      for (int i = 0; i < 4; ++i)
        pRow[(quad * 4 + i) * 136 + nf * 16 + m15] = f2bf(s[nf][i]);
    f32x4 o[4];
    #pragma unroll
    for (int nf = 0; nf < 4; ++nf) o[nf] = z;
    #pragma unroll
    for (int kc = 0; kc < 4; ++kc) {
      short8 pa = *(const short8*)(pRow + m15 * 136 + kc * 32 + quad * 8);
      #pragma unroll
      for (int nf = 0; nf < 4; ++nf) {
        short8 vb = *(const short8*)(VtL + (nf * 16 + m15) * 136 + kc * 32 + quad * 8);
        o[nf] = __builtin_amdgcn_mfma_f32_16x16x32_bf16(pa, vb, o[nf], 0, 0, 0);
      }
    }
    #pragma unroll
    for (int nf = 0; nf < 4; ++nf) {
      int c = h * 64 + nf * 16 + m15;
      size_t base = ((size_t)(c >> 5)) * 64 + ((c >> 3) & 3) * 16 + b;
      int cj = c & 7;
      #pragma unroll
      for (int i = 0; i < 4; ++i) {
        int qg = qt * 16 + quad * 4 + i;
        aout[(((size_t)qg * 8) * 64 + base) * 8 + cj] = f2bf(o[nf][i] * l[i]);
      }
    }
  }
}

// ============ gx heads only (table/hand heads fused into k_woffn) ============
__global__ __launch_bounds__(256, 4) void k_thg(
    const ushort_t* __restrict__ x2,
    const float* __restrict__ mw, const float* __restrict__ mbi,
    const float* __restrict__ sw, const float* __restrict__ sbi,
    const float* __restrict__ cw, const float* __restrict__ cbi,
    float* __restrict__ out)
{
  __shared__ float rowL[256];
  const int tid = threadIdx.x;
  int sb = blockIdx.x;                 // s*16 + b
  int s = sb >> 4, b = sb & 15;
  const ushort_t* row = x2 + ((size_t)(s * cHW + 292) * cB + b) * cC;
  rowL[tid] = bf2f(row[tid]);
  __syncthreads();
  int j = tid;
  if (j < 100) {
    const float* W;
    const float* Bi;
    int jj, M;
    size_t off;
    if (j < 20)      { W = mw; Bi = mbi; jj = j;      M = 20; off = 0;     }
    else if (j < 84) { W = sw; Bi = sbi; jj = j - 20; M = 64; off = 5120;  }
    else             { W = cw; Bi = cbi; jj = j - 84; M = 16; off = 21504; }
    float acc = Bi[jj];
    for (int c = 0; c < 256; ++c) acc = fmaf(rowL[c], W[c * M + jj], acc);
    out[off + (size_t)sb * M + jj] = acc;
  }
}

extern "C" void kernel_launch(void* const* d_in, const int* in_sizes, int n_in,
                              void* d_out, int out_size, void* d_ws, size_t ws_size,
                              hipStream_t stream)
{
  const int*   tq       = (const int*)d_in[0];
  const int*   pad_q    = (const int*)d_in[1];
  const float* xk       = (const float*)d_in[2];
  const int*   tk       = (const int*)d_in[3];
  const int*   pad_k    = (const int*)d_in[4];
  const float* spatial  = (const float*)d_in[8];
  const float* temporal = (const float*)d_in[9];
  const float* ln1_g    = (const float*)d_in[10];
  const float* ln1_b    = (const float*)d_in[11];
  const float* wq       = (const float*)d_in[12];
  const float* bq       = (const float*)d_in[13];
  const float* wk       = (const float*)d_in[14];
  const float* bk       = (const float*)d_in[15];
  const float* wv       = (const float*)d_in[16];
  const float* bv       = (const float*)d_in[17];
  const float* wo       = (const float*)d_in[18];
  const float* bo       = (const float*)d_in[19];
  const float* ln2_g    = (const float*)d_in[20];
  const float* ln2_b    = (const float*)d_in[21];
  const float* w1       = (const float*)d_in[22];
  const float* b1       = (const float*)d_in[23];
  const float* w2       = (const float*)d_in[24];
  const float* b2       = (const float*)d_in[25];
  const float* table_w  = (const float*)d_in[26];
  const float* table_b  = (const float*)d_in[27];
  const float* hand_w   = (const float*)d_in[28];
  const float* hand_b   = (const float*)d_in[29];
  const float* mode_w   = (const float*)d_in[30];
  const float* mode_b   = (const float*)d_in[31];
  const float* shape_w  = (const float*)d_in[32];
  const float* shape_b  = (const float*)d_in[33];
  const float* color_w  = (const float*)d_in[34];
  const float* color_b  = (const float*)d_in[35];
  float* out = (float*)d_out;

  char* ws = (char*)d_ws;
  const size_t NB2 = (size_t)cNN * cC * sizeof(ushort_t);      // 38,404,096
  ushort_t* buf1 = (ushort_t*)ws;                              // a_swz (attn out)
  ushort_t* buf2 = (ushort_t*)(ws + NB2);                      // Q -> x2 (gx rows)
  char* p = ws + 2 * NB2;
  ushort_t* Kb  = (ushort_t*)p;  p += (size_t)cLK * cB * 256 * 2;
  ushort_t* Vb  = (ushort_t*)p;  p += (size_t)cLK * cB * 256 * 2;
  ushort_t* xkb = (ushort_t*)p;  p += (size_t)cLK * cB * 256 * 2;
  ushort_t* wqs = (ushort_t*)p;  p += 256 * 256 * 2;
  ushort_t* wks = (ushort_t*)p;  p += 256 * 256 * 2;
  ushort_t* wvs = (ushort_t*)p;  p += 256 * 256 * 2;
  ushort_t* wos = (ushort_t*)p;  p += 256 * 256 * 2;
  ushort_t* w1s = (ushort_t*)p;  p += 256 * 1024 * 2;
  ushort_t* w2s = (ushort_t*)p;  p += 1024 * 256 * 2;
  ushort_t* tws = (ushort_t*)p;  p += 256 * 32 * 2;
  ushort_t* hws = (ushort_t*)p;  p += 256 * 32 * 2;

  k_prep<<<904, 256, 0, stream>>>(xk, xkb, wq, wqs, wk, wks, wv, wvs,
                                  wo, wos, w1, w1s, w2, w2s,
                                  table_w, tws, hand_w, hws);
  k_qnpkv<<<cNN / 64 + 64, 256, 0, stream>>>(tq, spatial, temporal, ln1_g, ln1_b,
                                             wqs, bq, buf2, xkb, wks, wvs,
                                             bk, bv, Kb, Vb);
  k_attn<<<dim3(19, cH, cB), 512, 0, stream>>>(buf2, Kb, Vb, tq, tk,
                                               pad_q, pad_k, buf1);
  k_woffn<<<cNN / 64, 512, 0, stream>>>(buf1, wos, bo, tq, spatial, temporal,
                                        ln2_g, ln2_b, w1s, b1, w2s, b2, buf2,
                                        tws, table_b, hws, hand_b, out);
  k_thg<<<cS * cB, 256, 0, stream>>>(buf2, mode_w, mode_b, shape_w, shape_b,
                                     color_w, color_b, out);
}

// Round 14
// 368.173 us; speedup vs baseline: 1.0803x; 1.0118x over previous
//
#include <hip/hip_runtime.h>
#include <hip/hip_bf16.h>

namespace {
constexpr int cS = 16, cB = 16, cC = 256, cH = 4, cDH = 64, cHW = 293;
constexpr int cLQ = cS * cHW;      // 4688
constexpr int cLK = 128;
constexpr int cNN = cLQ * cB;      // 75008
constexpr size_t TX_OFF = 25600;         // 5120 + 16384 + 4096
constexpr size_t HX_OFF = 2122752;       // TX_OFF + 16*16*2*64*64
}

typedef unsigned short ushort_t;
typedef unsigned int uint_t;
typedef __attribute__((ext_vector_type(8))) short short8;    // 8 bf16 (4 VGPRs)
typedef __attribute__((ext_vector_type(4))) float f32x4;     // MFMA C/D frag

__device__ __forceinline__ float bf2f(ushort_t u) {
  return __uint_as_float(((uint_t)u) << 16);
}
__device__ __forceinline__ ushort_t f2bf(float f) {
  __hip_bfloat16 h = __float2bfloat16(f);
  return *(ushort_t*)&h;
}

// SWZ frag-linear activation layout for a [rows][256] matrix:
// element (r, c) -> ((r>>4)*8 + (c>>5))*512 + ((c>>3)&3)*128 + (r&15)*8 + (c&7)
__device__ __forceinline__ size_t swz(int r, int c) {
  return (((size_t)(r >> 4) * 8 + (c >> 5)) * 64 + ((c >> 3) & 3) * 16 + (r & 15)) * 8 + (c & 7);
}

// ============ merged prep: xk cvt+swz, 8 weight swizzles ============
__global__ __launch_bounds__(256) void k_prep(
    const float* __restrict__ xk, ushort_t* __restrict__ xkb,
    const float* __restrict__ wq, ushort_t* __restrict__ wqs,
    const float* __restrict__ wk, ushort_t* __restrict__ wks,
    const float* __restrict__ wv, ushort_t* __restrict__ wvs,
    const float* __restrict__ wo, ushort_t* __restrict__ wos,
    const float* __restrict__ w1, ushort_t* __restrict__ w1s,
    const float* __restrict__ w2, ushort_t* __restrict__ w2s,
    const float* __restrict__ tw, ushort_t* __restrict__ tws,
    const float* __restrict__ hw_, ushort_t* __restrict__ hws)
{
  int bid = blockIdx.x;
  if (bid < 512) {
    int i4 = bid * 256 + threadIdx.x;
    int r = i4 >> 6;
    int c0 = (i4 & 63) * 4;
    float4 v = *(const float4*)(xk + (size_t)r * 256 + c0);
    ushort_t o[4] = {f2bf(v.x), f2bf(v.y), f2bf(v.z), f2bf(v.w)};
    *(uint2*)&xkb[swz(r, c0)] = *(uint2*)o;
    return;
  }
  int rr = bid - 512;
  const float* W; ushort_t* Ws; int N; int lb;
  if      (rr < 32)  { W = wq;  Ws = wqs; N = 256;  lb = rr; }
  else if (rr < 64)  { W = wk;  Ws = wks; N = 256;  lb = rr - 32; }
  else if (rr < 96)  { W = wv;  Ws = wvs; N = 256;  lb = rr - 64; }
  else if (rr < 128) { W = wo;  Ws = wos; N = 256;  lb = rr - 96; }
  else if (rr < 256) { W = w1;  Ws = w1s; N = 1024; lb = rr - 128; }
  else if (rr < 384) { W = w2;  Ws = w2s; N = 256;  lb = rr - 256; }
  else if (rr < 388) { W = tw;  Ws = tws; N = 32;   lb = rr - 384; }
  else               { W = hw_; Ws = hws; N = 32;   lb = rr - 388; }
  int slot = lb * 256 + threadIdx.x;
  int lane = slot & 63;
  int fr   = slot >> 6;
  int NB   = N >> 4;
  int nb   = fr % NB, kc = fr / NB;
  int n    = nb * 16 + (lane & 15);
  int k0   = kc * 32 + (lane >> 4) * 8;
  ushort_t tmp[8];
  #pragma unroll
  for (int i = 0; i < 8; ++i) tmp[i] = f2bf(W[(size_t)(k0 + i) * N + n]);
  *(uint4*)&Ws[(size_t)slot * 8] = *(uint4*)tmp;
}

// ============ core GEMM: 64 rows x (4x16 cols/wave), K=256, N-split waves ============
__device__ __forceinline__ void gemm_k256(
    const ushort_t* __restrict__ A, const ushort_t* __restrict__ Ws,
    int rt0, int slot0, int NB, int lane, f32x4 c[4][4])
{
  #pragma unroll 2
  for (int kc = 0; kc < 8; ++kc) {
    short8 a[4];
    #pragma unroll
    for (int mf = 0; mf < 4; ++mf)
      a[mf] = *(const short8*)(A + (((size_t)(rt0 + mf) * 8 + kc) * 64 + lane) * 8);
    #pragma unroll
    for (int nb = 0; nb < 4; ++nb) {
      short8 b = *(const short8*)(Ws + (((size_t)kc * NB + slot0 + nb) * 64 + lane) * 8);
      #pragma unroll
      for (int mf = 0; mf < 4; ++mf)
        c[mf][nb] = __builtin_amdgcn_mfma_f32_16x16x32_bf16(a[mf], b, c[mf][nb], 0, 0, 0);
    }
  }
}

// ============ merged: fused xq+LN1+Q-projection (bid<1172) OR K/V proj (bid>=1172) ====
// R13: LN1 quad-parallel (4 rows in flight, 4-step shfl within 16 lanes).
__global__ __launch_bounds__(256, 4) void k_qnpkv(
    const int* __restrict__ tq, const float* __restrict__ spatial,
    const float* __restrict__ temporal, const float* __restrict__ g,
    const float* __restrict__ bt, const ushort_t* __restrict__ wqs,
    const float* __restrict__ bq, ushort_t* __restrict__ Out,
    const ushort_t* __restrict__ xkb, const ushort_t* __restrict__ wks,
    const ushort_t* __restrict__ wvs, const float* __restrict__ bk,
    const float* __restrict__ bv, ushort_t* __restrict__ Kb,
    ushort_t* __restrict__ Vb)
{
  __shared__ ushort_t aT[64 * 256];    // A frags, then reused as epilogue tile
  const int NQ = cNN / 64;             // 1172
  const int tid = threadIdx.x, lane = tid & 63, w = tid >> 6;
  const int lane15 = lane & 15, kq = lane >> 4;
  f32x4 z = {0.f, 0.f, 0.f, 0.f};

  if ((int)blockIdx.x >= NQ) {
    // ---- K/V projection path
    int bid2 = blockIdx.x - NQ;        // 0..63
    const ushort_t* Ws = (bid2 >> 5) ? wvs : wks;
    const float* Bi = (bid2 >> 5) ? bv : bk;
    ushort_t* Kv = (bid2 >> 5) ? Vb : Kb;
    const int bx = bid2 & 31;
    const int rt0 = bx * 4, row0 = bx * 64;
    f32x4 c[4][4];
    #pragma unroll
    for (int mf = 0; mf < 4; ++mf)
      #pragma unroll
      for (int nb = 0; nb < 4; ++nb) c[mf][nb] = z;
    gemm_k256(xkb, Ws, rt0, w * 4, 16, lane, c);
    #pragma unroll
    for (int nb = 0; nb < 4; ++nb) {
      int col = w * 64 + nb * 16 + lane15;
      float bias = Bi[col];
      #pragma unroll
      for (int mf = 0; mf < 4; ++mf)
        #pragma unroll
        for (int i = 0; i < 4; ++i) {
          int row = row0 + mf * 16 + kq * 4 + i;
          Kv[(size_t)row * 256 + col] = f2bf(c[mf][nb][i] + bias);
        }
    }
    return;
  }

  // ---- xq + LN1 + Q-projection path
  const int rt0 = blockIdx.x * 4, row0 = blockIdx.x * 64;
  {
    int q = rt0 + w;                   // wave-uniform
    int s = q / cHW, hw = q % cHW;
    const int quad4 = lane >> 4;       // row within group of 4
    #pragma unroll 1
    for (int rrg = 0; rrg < 4; ++rrg) {
      int rr = rrg * 4 + quad4;
      int t = tq[s * cB + rr];
      float4 v[4];
      float sum = 0.f, sum2 = 0.f;
      #pragma unroll
      for (int ch = 0; ch < 4; ++ch) {
        int c0 = ch * 64 + lane15 * 4;
        float4 tv = *(const float4*)(temporal + (size_t)t * cC + c0);
        float4 sv = *(const float4*)(spatial + (size_t)hw * cC + c0);
        float4 vv;
        vv.x = tv.x + sv.x; vv.y = tv.y + sv.y;
        vv.z = tv.z + sv.z; vv.w = tv.w + sv.w;
        v[ch] = vv;
        sum  += vv.x + vv.y + vv.z + vv.w;
        sum2 += vv.x * vv.x + vv.y * vv.y + vv.z * vv.z + vv.w * vv.w;
      }
      #pragma unroll
      for (int off = 8; off >= 1; off >>= 1) {
        sum  += __shfl_xor(sum,  off, 64);
        sum2 += __shfl_xor(sum2, off, 64);
      }
      float mean = sum * (1.0f / cC);
      float var  = sum2 * (1.0f / cC) - mean * mean;
      float inv  = rsqrtf(var + 1e-5f);
      #pragma unroll
      for (int ch = 0; ch < 4; ++ch) {
        int c0 = ch * 64 + lane15 * 4;
        float4 g4 = *(const float4*)(g + c0);
        float4 b4 = *(const float4*)(bt + c0);
        int kc = c0 >> 5, qq = (c0 >> 3) & 3, joff = c0 & 7;
        ushort_t o[4] = {f2bf((v[ch].x - mean) * inv * g4.x + b4.x),
                         f2bf((v[ch].y - mean) * inv * g4.y + b4.y),
                         f2bf((v[ch].z - mean) * inv * g4.z + b4.z),
                         f2bf((v[ch].w - mean) * inv * g4.w + b4.w)};
        *(uint2*)&aT[(((w * 8 + kc) * 64) + qq * 16 + rr) * 8 + joff] = *(uint2*)o;
      }
    }
  }
  __syncthreads();
  f32x4 c[4][4];
  #pragma unroll
  for (int mf = 0; mf < 4; ++mf)
    #pragma unroll
    for (int nb = 0; nb < 4; ++nb) c[mf][nb] = z;
  gemm_k256(aT, wqs, 0, w * 4, 16, lane, c);
  __syncthreads();                     // all aT frag reads complete
  #pragma unroll
  for (int nb = 0; nb < 4; ++nb) {
    int col = w * 64 + nb * 16 + lane15;
    float bias = bq[col];
    #pragma unroll
    for (int mf = 0; mf < 4; ++mf)
      #pragma unroll
      for (int i = 0; i < 4; ++i)
        aT[(mf * 16 + kq * 4 + i) * 256 + col] = f2bf(c[mf][nb][i] + bias);
  }
  __syncthreads();
  uint2* outp = (uint2*)(Out + (size_t)row0 * 256);
  #pragma unroll
  for (int it = 0; it < 16; ++it) {
    int f = tid + it * 256;
    int row = f >> 6, c0 = (f & 63) * 4;
    outp[f] = *(uint2*)&aT[row * 256 + c0];
  }
}

// ============ MEGA-FUSED: wo proj + xq resid + LN2 + FFN1 + GELU + FFN2 + resid
//              + table/hand heads (fused from k_thg) ====
// R10 base (k_woffn 181us). R14 change: SWAPPED-OPERAND FFN1 (mfma(wf, a) ->
// D[h-col][x-row]) so each thread owns 4 consecutive h-cols and the GELU
// output is 4x ds_write_b64 per thread per chunk instead of 16x ds_write_b16
// (R3-proven semantics; register-neutral: c1 is still 4x f32x4).
// Do not deepen per-block pipelining (R2/R11: costs 2-block co-residency).
__global__ __launch_bounds__(512, 8) void k_woffn(
    const ushort_t* __restrict__ A, const ushort_t* __restrict__ wos,
    const float* __restrict__ bo, const int* __restrict__ tq,
    const float* __restrict__ spatial, const float* __restrict__ temporal,
    const float* __restrict__ g, const float* __restrict__ bt,
    const ushort_t* __restrict__ w1s, const float* __restrict__ b1,
    const ushort_t* __restrict__ w2s, const float* __restrict__ b2,
    ushort_t* __restrict__ x2out,
    const ushort_t* __restrict__ tws, const float* __restrict__ tb,
    const ushort_t* __restrict__ hws, const float* __restrict__ hb,
    float* __restrict__ out)
{
  __shared__ ushort_t aT[64 * 264];     // frag use: first 16384 elems; epilogue stride 264
  __shared__ ushort_t hL0[64 * 128];    // h ping buffer (16KB); LN2 scratch aliased
  __shared__ ushort_t hL1[64 * 128];    // h pong buffer (16KB)
  float (*red)[64][2] = (float (*)[64][2])hL0;       // 8*64*2*4 = 4096 B
  float* meanL = (float*)hL0 + 1024;                 // +4096 B
  float* invL  = meanL + 64;                         // ends < 16384
  const int tid = threadIdx.x, lane = tid & 63, w = tid >> 6;   // w in [0,8)
  const int lane15 = lane & 15, kq = lane >> 4;
  const int rt0 = blockIdx.x * 4, row0 = blockIdx.x * 64;
  const f32x4 z = {0.f, 0.f, 0.f, 0.f};

  // ---- Phase 1: wo GEMM, cc[4][2] over wave's 32 cols
  f32x4 cc[4][2];   // wo-GEMM -> residual carrier -> FFN2 accumulates ON TOP
  #pragma unroll
  for (int mf = 0; mf < 4; ++mf)
    #pragma unroll
    for (int nb = 0; nb < 2; ++nb) cc[mf][nb] = z;
  #pragma unroll 1
  for (int kc = 0; kc < 8; ++kc) {
    short8 a[4];
    #pragma unroll
    for (int mf = 0; mf < 4; ++mf)
      a[mf] = *(const short8*)(A + (((size_t)(rt0 + mf) * 8 + kc) * 64 + lane) * 8);
    #pragma unroll
    for (int nb = 0; nb < 2; ++nb) {
      short8 b = *(const short8*)(wos + (((size_t)kc * 16 + w * 2 + nb) * 64 + lane) * 8);
      #pragma unroll
      for (int mf = 0; mf < 4; ++mf)
        cc[mf][nb] = __builtin_amdgcn_mfma_f32_16x16x32_bf16(a[mf], b, cc[mf][nb], 0, 0, 0);
    }
  }
  // ---- + bias + xq (recomputed): cc now holds the residual x in f32
  {
    int tt[4][4], hws_[4];
    #pragma unroll
    for (int mf = 0; mf < 4; ++mf) {
      int q = rt0 + mf;
      int s = q / cHW;
      hws_[mf] = q % cHW;
      #pragma unroll
      for (int i = 0; i < 4; ++i) tt[mf][i] = tq[s * cB + kq * 4 + i];
    }
    #pragma unroll
    for (int nb = 0; nb < 2; ++nb) {
      int col = w * 32 + nb * 16 + lane15;
      float bias = bo[col];
      #pragma unroll
      for (int mf = 0; mf < 4; ++mf) {
        float sp = spatial[(size_t)hws_[mf] * cC + col];
        #pragma unroll
        for (int i = 0; i < 4; ++i)
          cc[mf][nb][i] += bias + temporal[(size_t)tt[mf][i] * cC + col] + sp;
      }
    }
  }
  // ---- Phase 2: LN2 stats (cross-wave; scratch lives in hL0 alias)
  #pragma unroll
  for (int mf = 0; mf < 4; ++mf)
    #pragma unroll
    for (int i = 0; i < 4; ++i) {
      float s4 = cc[mf][0][i] + cc[mf][1][i];
      float q4 = cc[mf][0][i] * cc[mf][0][i] + cc[mf][1][i] * cc[mf][1][i];
      #pragma unroll
      for (int off = 8; off >= 1; off >>= 1) {
        s4 += __shfl_xor(s4, off, 64);
        q4 += __shfl_xor(q4, off, 64);
      }
      if (lane15 == 0) {
        red[w][mf * 16 + kq * 4 + i][0] = s4;
        red[w][mf * 16 + kq * 4 + i][1] = q4;
      }
    }
  __syncthreads();
  if (tid < 64) {
    float S = 0.f, Q = 0.f;
    #pragma unroll
    for (int ww = 0; ww < 8; ++ww) { S += red[ww][tid][0]; Q += red[ww][tid][1]; }
    float m = S * (1.0f / cC);
    float v = Q * (1.0f / cC) - m * m;
    meanL[tid] = m;
    invL[tid] = rsqrtf(v + 1e-5f);
  }
  __syncthreads();
  // ---- Phase 3: xln -> aT frag layout ONLY (cc keeps x; no global stash)
  #pragma unroll
  for (int nb = 0; nb < 2; ++nb) {
    int col = w * 32 + nb * 16 + lane15;
    float gc = g[col], bc = bt[col];
    int qd = nb * 2 + (lane15 >> 3);   // (col&31)>>3
    int jd = lane15 & 7;
    #pragma unroll
    for (int mf = 0; mf < 4; ++mf)
      #pragma unroll
      for (int i = 0; i < 4; ++i) {
        int rl = mf * 16 + kq * 4 + i;
        float lv = (cc[mf][nb][i] - meanL[rl]) * invL[rl] * gc + bc;
        aT[((mf * 8 + w) * 64 + qd * 16 + kq * 4 + i) * 8 + jd] = f2bf(lv);
      }
  }
  __syncthreads();                     // aT ready; meanL/invL dead (hL0 reusable)
  // ---- Phase 4: FFN loop, 8 chunks of 128 h-cols; h ping-pong hL0/hL1.
  // One barrier per chunk: GELU-write(c) to buf[c&1] is separated from
  // FFN2(c-2)'s reads of the same buf by barrier(c-1).
  #pragma unroll 1
  for (int hc2 = 0; hc2 < 8; ++hc2) {
    ushort_t* hB = (hc2 & 1) ? hL1 : hL0;
    // FFN1 (SWAPPED operands): c1[xt] = D[h-col][x-row].
    // Wave w computes h cols [hc2*128 + w*16, +16) x all 64 x-rows.
    f32x4 c1[4];
    #pragma unroll
    for (int xt = 0; xt < 4; ++xt) c1[xt] = z;
    const int slot = hc2 * 8 + w;
    #pragma unroll 1
    for (int kc = 0; kc < 8; ++kc) {
      short8 wf = *(const short8*)(w1s + (((size_t)kc * 64 + slot) * 64 + lane) * 8);
      #pragma unroll
      for (int xt = 0; xt < 4; ++xt) {
        short8 a = *(const short8*)&aT[((xt * 8 + kc) * 64 + lane) * 8];
        c1[xt] = __builtin_amdgcn_mfma_f32_16x16x32_bf16(wf, a, c1[xt], 0, 0, 0);
      }
    }
    // GELU = x * sigmoid(2u) [exact identity]; thread owns 4 consecutive
    // h-cols (w*16+kq*4+i) per x-row-tile -> one ds_write_b64 per xt.
    {
      float4 b4 = *(const float4*)(b1 + hc2 * 128 + w * 16 + kq * 4);
      const int base = (w >> 1) * 2048 + (((w * 2) + (kq >> 1)) & 3) * 128
                     + lane15 * 8 + (kq & 1) * 4;
      #pragma unroll
      for (int xt = 0; xt < 4; ++xt) {
        ushort_t o[4];
        #pragma unroll
        for (int i = 0; i < 4; ++i) {
          float xx = c1[xt][i] + ((const float*)&b4)[i];
          float x2v = xx * xx;
          float mm = fmaf(x2v, 0.044715f, 1.0f);
          float u2 = xx * mm * -1.5957691216057308f;   // -2*sqrt(2/pi)
          float e = __expf(u2);
          float ge = xx * __builtin_amdgcn_rcpf(1.0f + e);
          o[i] = f2bf(ge);
        }
        *(uint2*)&hB[base + xt * 512] = *(uint2*)o;
      }
    }
    __syncthreads();                  // hB chunk ready
    // FFN2: K=128 (4 kc2), wave cols [w*32,+32), accumulate into cc (resid inside)
    #pragma unroll 1
    for (int kc2 = 0; kc2 < 4; ++kc2) {
      short8 a2[4];
      #pragma unroll
      for (int mf = 0; mf < 4; ++mf)
        a2[mf] = *(const short8*)&hB[((kc2 * 4 + mf) * 64 + lane) * 8];
      #pragma unroll
      for (int nb = 0; nb < 2; ++nb) {
        short8 b = *(const short8*)(w2s +
            (((size_t)(hc2 * 4 + kc2) * 16 + w * 2 + nb) * 64 + lane) * 8);
        #pragma unroll
        for (int mf = 0; mf < 4; ++mf)
          cc[mf][nb] = __builtin_amdgcn_mfma_f32_16x16x32_bf16(a2[mf], b, cc[mf][nb], 0, 0, 0);
      }
    }
  }
  __syncthreads();                     // all aT/hL frag reads complete
  // ---- Phase 5: cc (= x + FFN) + b2 -> aT row-major STRIDE 264
  #pragma unroll
  for (int nb = 0; nb < 2; ++nb) {
    int col = w * 32 + nb * 16 + lane15;
    float bias = b2[col];
    #pragma unroll
    for (int mf = 0; mf < 4; ++mf)
      #pragma unroll
      for (int i = 0; i < 4; ++i)
        aT[(mf * 16 + kq * 4 + i) * 264 + col] = f2bf(cc[mf][nb][i] + bias);
  }
  __syncthreads();
  // ---- gx-row x2 write (only rows the gx kernel reads: q%293==292)
  #pragma unroll
  for (int mf = 0; mf < 4; ++mf) {
    if ((rt0 + mf) % cHW == 292) {
      for (int f = tid; f < 1024; f += 512) {
        int rl = mf * 16 + (f >> 6), c4 = (f & 63) * 4;
        *(uint2*)&x2out[(size_t)(row0 + rl) * 256 + c4] = *(uint2*)&aT[rl * 264 + c4];
      }
    }
  }
  // ---- fused table/hand heads: waves 0-3 table (rows (w&3)*16), 4-7 hand
  {
    const int wl = w & 3;
    const bool isHand = (w >= 4);
    const ushort_t* Ws = isHand ? hws : tws;
    const float* Bi = isHand ? hb : tb;
    f32x4 ct[2];
    ct[0] = z; ct[1] = z;
    const ushort_t* arow = aT + (wl * 16 + lane15) * 264 + kq * 8;
    #pragma unroll
    for (int kc = 0; kc < 8; ++kc) {
      short8 a = *(const short8*)(arow + kc * 32);
      #pragma unroll
      for (int nb = 0; nb < 2; ++nb) {
        short8 bf_ = *(const short8*)(Ws + (((size_t)(kc * 2 + nb)) * 64 + lane) * 8);
        ct[nb] = __builtin_amdgcn_mfma_f32_16x16x32_bf16(a, bf_, ct[nb], 0, 0, 0);
      }
    }
    #pragma unroll
    for (int nb = 0; nb < 2; ++nb) {
      int j = nb * 16 + lane15;
      float bias = Bi[j];
      int uh = j >> 3, uw = (j >> 1) & 3, uc = j & 1;
      #pragma unroll
      for (int i = 0; i < 4; ++i) {
        int rg = row0 + wl * 16 + kq * 4 + i;
        int b = rg & 15, q = rg >> 4;
        int s = (q * 3579) >> 20;          // exact q/293 for q<14768
        int hw = q - s * cHW;
        if (!isHand && hw < 256) {
          int th = hw >> 4, twi = hw & 15;
          size_t idx = TX_OFF +
              ((((size_t)(s * cB + b)) * 2 + uc) * 64 + (th * 4 + uh)) * 64 + (twi * 4 + uw);
          out[idx] = ct[nb][i] + bias;
        } else if (isHand && hw >= 256 && hw < 292) {
          int h2 = hw - 256;
          int hh = h2 / 6, ww = h2 % 6;
          size_t idx = HX_OFF +
              ((((size_t)(s * cB + b)) * 2 + uc) * 24 + (hh * 4 + uh)) * 24 + (ww * 4 + uw);
          out[idx] = ct[nb][i] + bias;
        }
      }
    }
  }
}

// ============ MFMA attention: 512 threads, per (b,h), 16 q-tiles per block ============
__global__ __launch_bounds__(512, 4) void k_attn(
    const ushort_t* __restrict__ Qb, const ushort_t* __restrict__ Kb,
    const ushort_t* __restrict__ Vb, const int* __restrict__ tq,
    const int* __restrict__ tk, const int* __restrict__ pad_q,
    const int* __restrict__ pad_k, ushort_t* __restrict__ aout)
{
  __shared__ ushort_t KL[128 * 72];     // [k][d]
  __shared__ ushort_t VtL[64 * 136];    // [d][k]
  __shared__ ushort_t pL[8][16 * 136];  // per-wave P tile
  __shared__ int tkL[128];

  const int h = blockIdx.y, b = blockIdx.z;
  const int tid = threadIdx.x, lane = tid & 63, w = tid >> 6;   // w in [0,8)
  const int m15 = lane & 15, quad = lane >> 4;

  for (int i = tid; i < 128 * 16; i += 512) {
    int k = i >> 4, d4 = (i & 15) * 4;
    size_t src = (size_t)(k * cB + b) * 256 + h * 64 + d4;
    uint2 kv = *(const uint2*)&Kb[src];
    uint2 vv = *(const uint2*)&Vb[src];
    *(uint2*)&KL[k * 72 + d4] = kv;
    const ushort_t* vvp = (const ushort_t*)&vv;
    #pragma unroll
    for (int t = 0; t < 4; ++t) VtL[(d4 + t) * 136 + k] = vvp[t];
  }
  if (tid < 128) tkL[tid] = tk[tid * cB + b];
  __syncthreads();
  const int pk = pad_k[b];
  const int pq = pad_q[b] * cHW;
  ushort_t* pRow = pL[w];
  const f32x4 z = {0.f, 0.f, 0.f, 0.f};

  for (int pr = 0; pr < 2; ++pr) {
    int qt = blockIdx.x * 16 + pr * 8 + w;
    if (qt >= 293) break;                       // wave-uniform
    const ushort_t* qrow =
        Qb + ((size_t)((qt * 16 + m15) * cB + b)) * 256 + h * 64 + quad * 8;
    short8 qa0 = *(const short8*)(qrow);
    short8 qa1 = *(const short8*)(qrow + 32);
    f32x4 s[8];
    #pragma unroll
    for (int nf = 0; nf < 8; ++nf) {
      const ushort_t* kp = KL + (nf * 16 + m15) * 72 + quad * 8;
      short8 b0 = *(const short8*)(kp);
      short8 b1 = *(const short8*)(kp + 32);
      s[nf] = __builtin_amdgcn_mfma_f32_16x16x32_bf16(qa0, b0, z, 0, 0, 0);
      s[nf] = __builtin_amdgcn_mfma_f32_16x16x32_bf16(qa1, b1, s[nf], 0, 0, 0);
    }
    int tqv[4], qok[4];
    #pragma unroll
    for (int i = 0; i < 4; ++i) {
      int qg = qt * 16 + quad * 4 + i;
      int sidx = (qg * 3579) >> 20;            // exact q/293 for q<14768
      tqv[i] = tq[sidx * cB + b];
      qok[i] = (qg < pq);
    }
    #pragma unroll
    for (int nf = 0; nf < 8; ++nf) {
      int kidx = nf * 16 + m15;
      int tkc = tkL[kidx];
      bool kok = (kidx < pk);
      #pragma unroll
      for (int i = 0; i < 4; ++i) {
        bool ok = kok && qok[i] && (tkc <= tqv[i]);
        s[nf][i] = ok ? s[nf][i] * 0.125f : -1e9f;
      }
    }
    float mx[4], l[4];
    #pragma unroll
    for (int i = 0; i < 4; ++i) {
      float m = s[0][i];
      #pragma unroll
      for (int nf = 1; nf < 8; ++nf) m = fmaxf(m, s[nf][i]);
      #pragma unroll
      for (int off = 8; off >= 1; off >>= 1) m = fmaxf(m, __shfl_xor(m, off, 64));
      mx[i] = m;
    }
    #pragma unroll
    for (int i = 0; i < 4; ++i) l[i] = 0.f;
    #pragma unroll
    for (int nf = 0; nf < 8; ++nf)
      #pragma unroll
      for (int i = 0; i < 4; ++i) {
        float p = __expf(s[nf][i] - mx[i]);
        s[nf][i] = p;
        l[i] += p;
      }
    #pragma unroll
    for (int i = 0; i < 4; ++i) {
      float t = l[i];
      #pragma unroll
      for (int off = 8; off >= 1; off >>= 1) t += __shfl_xor(t, off, 64);
      l[i] = 1.0f / t;
    }
    #pragma unroll
    for (int nf = 0; nf < 8; ++nf)
      #pragma unroll
      for (int i = 0; i < 4; ++i)
        pRow[(quad * 4 + i) * 136 + nf * 16 + m15] = f2bf(s[nf][i]);
    f32x4 o[4];
    #pragma unroll
    for (int nf = 0; nf < 4; ++nf) o[nf] = z;
    #pragma unroll
    for (int kc = 0; kc < 4; ++kc) {
      short8 pa = *(const short8*)(pRow + m15 * 136 + kc * 32 + quad * 8);
      #pragma unroll
      for (int nf = 0; nf < 4; ++nf) {
        short8 vb = *(const short8*)(VtL + (nf * 16 + m15) * 136 + kc * 32 + quad * 8);
        o[nf] = __builtin_amdgcn_mfma_f32_16x16x32_bf16(pa, vb, o[nf], 0, 0, 0);
      }
    }
    #pragma unroll
    for (int nf = 0; nf < 4; ++nf) {
      int c = h * 64 + nf * 16 + m15;
      size_t base = ((size_t)(c >> 5)) * 64 + ((c >> 3) & 3) * 16 + b;
      int cj = c & 7;
      #pragma unroll
      for (int i = 0; i < 4; ++i) {
        int qg = qt * 16 + quad * 4 + i;
        aout[(((size_t)qg * 8) * 64 + base) * 8 + cj] = f2bf(o[nf][i] * l[i]);
      }
    }
  }
}

// ============ gx heads only (table/hand heads fused into k_woffn) ============
__global__ __launch_bounds__(256, 4) void k_thg(
    const ushort_t* __restrict__ x2,
    const float* __restrict__ mw, const float* __restrict__ mbi,
    const float* __restrict__ sw, const float* __restrict__ sbi,
    const float* __restrict__ cw, const float* __restrict__ cbi,
    float* __restrict__ out)
{
  __shared__ float rowL[256];
  const int tid = threadIdx.x;
  int sb = blockIdx.x;                 // s*16 + b
  int s = sb >> 4, b = sb & 15;
  const ushort_t* row = x2 + ((size_t)(s * cHW + 292) * cB + b) * cC;
  rowL[tid] = bf2f(row[tid]);
  __syncthreads();
  int j = tid;
  if (j < 100) {
    const float* W;
    const float* Bi;
    int jj, M;
    size_t off;
    if (j < 20)      { W = mw; Bi = mbi; jj = j;      M = 20; off = 0;     }
    else if (j < 84) { W = sw; Bi = sbi; jj = j - 20; M = 64; off = 5120;  }
    else             { W = cw; Bi = cbi; jj = j - 84; M = 16; off = 21504; }
    float acc = Bi[jj];
    for (int c = 0; c < 256; ++c) acc = fmaf(rowL[c], W[c * M + jj], acc);
    out[off + (size_t)sb * M + jj] = acc;
  }
}

extern "C" void kernel_launch(void* const* d_in, const int* in_sizes, int n_in,
                              void* d_out, int out_size, void* d_ws, size_t ws_size,
                              hipStream_t stream)
{
  const int*   tq       = (const int*)d_in[0];
  const int*   pad_q    = (const int*)d_in[1];
  const float* xk       = (const float*)d_in[2];
  const int*   tk       = (const int*)d_in[3];
  const int*   pad_k    = (const int*)d_in[4];
  const float* spatial  = (const float*)d_in[8];
  const float* temporal = (const float*)d_in[9];
  const float* ln1_g    = (const float*)d_in[10];
  const float* ln1_b    = (const float*)d_in[11];
  const float* wq       = (const float*)d_in[12];
  const float* bq       = (const float*)d_in[13];
  const float* wk       = (const float*)d_in[14];
  const float* bk       = (const float*)d_in[15];
  const float* wv       = (const float*)d_in[16];
  const float* bv       = (const float*)d_in[17];
  const float* wo       = (const float*)d_in[18];
  const float* bo       = (const float*)d_in[19];
  const float* ln2_g    = (const float*)d_in[20];
  const float* ln2_b    = (const float*)d_in[21];
  const float* w1       = (const float*)d_in[22];
  const float* b1       = (const float*)d_in[23];
  const float* w2       = (const float*)d_in[24];
  const float* b2       = (const float*)d_in[25];
  const float* table_w  = (const float*)d_in[26];
  const float* table_b  = (const float*)d_in[27];
  const float* hand_w   = (const float*)d_in[28];
  const float* hand_b   = (const float*)d_in[29];
  const float* mode_w   = (const float*)d_in[30];
  const float* mode_b   = (const float*)d_in[31];
  const float* shape_w  = (const float*)d_in[32];
  const float* shape_b  = (const float*)d_in[33];
  const float* color_w  = (const float*)d_in[34];
  const float* color_b  = (const float*)d_in[35];
  float* out = (float*)d_out;

  char* ws = (char*)d_ws;
  const size_t NB2 = (size_t)cNN * cC * sizeof(ushort_t);      // 38,404,096
  ushort_t* buf1 = (ushort_t*)ws;                              // a_swz (attn out)
  ushort_t* buf2 = (ushort_t*)(ws + NB2);                      // Q -> x2 (gx rows)
  char* p = ws + 2 * NB2;
  ushort_t* Kb  = (ushort_t*)p;  p += (size_t)cLK * cB * 256 * 2;
  ushort_t* Vb  = (ushort_t*)p;  p += (size_t)cLK * cB * 256 * 2;
  ushort_t* xkb = (ushort_t*)p;  p += (size_t)cLK * cB * 256 * 2;
  ushort_t* wqs = (ushort_t*)p;  p += 256 * 256 * 2;
  ushort_t* wks = (ushort_t*)p;  p += 256 * 256 * 2;
  ushort_t* wvs = (ushort_t*)p;  p += 256 * 256 * 2;
  ushort_t* wos = (ushort_t*)p;  p += 256 * 256 * 2;
  ushort_t* w1s = (ushort_t*)p;  p += 256 * 1024 * 2;
  ushort_t* w2s = (ushort_t*)p;  p += 1024 * 256 * 2;
  ushort_t* tws = (ushort_t*)p;  p += 256 * 32 * 2;
  ushort_t* hws = (ushort_t*)p;  p += 256 * 32 * 2;

  k_prep<<<904, 256, 0, stream>>>(xk, xkb, wq, wqs, wk, wks, wv, wvs,
                                  wo, wos, w1, w1s, w2, w2s,
                                  table_w, tws, hand_w, hws);
  k_qnpkv<<<cNN / 64 + 64, 256, 0, stream>>>(tq, spatial, temporal, ln1_g, ln1_b,
                                             wqs, bq, buf2, xkb, wks, wvs,
                                             bk, bv, Kb, Vb);
  k_attn<<<dim3(19, cH, cB), 512, 0, stream>>>(buf2, Kb, Vb, tq, tk,
                                               pad_q, pad_k, buf1);
  k_woffn<<<cNN / 64, 512, 0, stream>>>(buf1, wos, bo, tq, spatial, temporal,
                                        ln2_g, ln2_b, w1s, b1, w2s, b2, buf2,
                                        tws, table_b, hws, hand_b, out);
  k_thg<<<cS * cB, 256, 0, stream>>>(buf2, mode_w, mode_b, shape_w, shape_b,
                                     color_w, color_b, out);
}

// Round 15
// 361.611 us; speedup vs baseline: 1.0999x; 1.0181x over previous
//
#include <hip/hip_runtime.h>
#include <hip/hip_bf16.h>

namespace {
constexpr int cS = 16, cB = 16, cC = 256, cH = 4, cDH = 64, cHW = 293;
constexpr int cLQ = cS * cHW;      // 4688
constexpr int cLK = 128;
constexpr int cNN = cLQ * cB;      // 75008
constexpr size_t TX_OFF = 25600;         // 5120 + 16384 + 4096
constexpr size_t HX_OFF = 2122752;       // TX_OFF + 16*16*2*64*64
}

typedef unsigned short ushort_t;
typedef unsigned int uint_t;
typedef __attribute__((ext_vector_type(8))) short short8;    // 8 bf16 (4 VGPRs)
typedef __attribute__((ext_vector_type(4))) float f32x4;     // MFMA C/D frag

__device__ __forceinline__ float bf2f(ushort_t u) {
  return __uint_as_float(((uint_t)u) << 16);
}
__device__ __forceinline__ ushort_t f2bf(float f) {
  __hip_bfloat16 h = __float2bfloat16(f);
  return *(ushort_t*)&h;
}

// SWZ frag-linear activation layout for a [rows][256] matrix:
// element (r, c) -> ((r>>4)*8 + (c>>5))*512 + ((c>>3)&3)*128 + (r&15)*8 + (c&7)
__device__ __forceinline__ size_t swz(int r, int c) {
  return (((size_t)(r >> 4) * 8 + (c >> 5)) * 64 + ((c >> 3) & 3) * 16 + (r & 15)) * 8 + (c & 7);
}

// ============ merged prep: xk cvt+swz, 8 weight swizzles ============
__global__ __launch_bounds__(256) void k_prep(
    const float* __restrict__ xk, ushort_t* __restrict__ xkb,
    const float* __restrict__ wq, ushort_t* __restrict__ wqs,
    const float* __restrict__ wk, ushort_t* __restrict__ wks,
    const float* __restrict__ wv, ushort_t* __restrict__ wvs,
    const float* __restrict__ wo, ushort_t* __restrict__ wos,
    const float* __restrict__ w1, ushort_t* __restrict__ w1s,
    const float* __restrict__ w2, ushort_t* __restrict__ w2s,
    const float* __restrict__ tw, ushort_t* __restrict__ tws,
    const float* __restrict__ hw_, ushort_t* __restrict__ hws)
{
  int bid = blockIdx.x;
  if (bid < 512) {
    int i4 = bid * 256 + threadIdx.x;
    int r = i4 >> 6;
    int c0 = (i4 & 63) * 4;
    float4 v = *(const float4*)(xk + (size_t)r * 256 + c0);
    ushort_t o[4] = {f2bf(v.x), f2bf(v.y), f2bf(v.z), f2bf(v.w)};
    *(uint2*)&xkb[swz(r, c0)] = *(uint2*)o;
    return;
  }
  int rr = bid - 512;
  const float* W; ushort_t* Ws; int N; int lb;
  if      (rr < 32)  { W = wq;  Ws = wqs; N = 256;  lb = rr; }
  else if (rr < 64)  { W = wk;  Ws = wks; N = 256;  lb = rr - 32; }
  else if (rr < 96)  { W = wv;  Ws = wvs; N = 256;  lb = rr - 64; }
  else if (rr < 128) { W = wo;  Ws = wos; N = 256;  lb = rr - 96; }
  else if (rr < 256) { W = w1;  Ws = w1s; N = 1024; lb = rr - 128; }
  else if (rr < 384) { W = w2;  Ws = w2s; N = 256;  lb = rr - 256; }
  else if (rr < 388) { W = tw;  Ws = tws; N = 32;   lb = rr - 384; }
  else               { W = hw_; Ws = hws; N = 32;   lb = rr - 388; }
  int slot = lb * 256 + threadIdx.x;
  int lane = slot & 63;
  int fr   = slot >> 6;
  int NB   = N >> 4;
  int nb   = fr % NB, kc = fr / NB;
  int n    = nb * 16 + (lane & 15);
  int k0   = kc * 32 + (lane >> 4) * 8;
  ushort_t tmp[8];
  #pragma unroll
  for (int i = 0; i < 8; ++i) tmp[i] = f2bf(W[(size_t)(k0 + i) * N + n]);
  *(uint4*)&Ws[(size_t)slot * 8] = *(uint4*)tmp;
}

// ============ core GEMM: 64 rows x (4x16 cols/wave), K=256, N-split waves ============
__device__ __forceinline__ void gemm_k256(
    const ushort_t* __restrict__ A, const ushort_t* __restrict__ Ws,
    int rt0, int slot0, int NB, int lane, f32x4 c[4][4])
{
  #pragma unroll 2
  for (int kc = 0; kc < 8; ++kc) {
    short8 a[4];
    #pragma unroll
    for (int mf = 0; mf < 4; ++mf)
      a[mf] = *(const short8*)(A + (((size_t)(rt0 + mf) * 8 + kc) * 64 + lane) * 8);
    #pragma unroll
    for (int nb = 0; nb < 4; ++nb) {
      short8 b = *(const short8*)(Ws + (((size_t)kc * NB + slot0 + nb) * 64 + lane) * 8);
      #pragma unroll
      for (int mf = 0; mf < 4; ++mf)
        c[mf][nb] = __builtin_amdgcn_mfma_f32_16x16x32_bf16(a[mf], b, c[mf][nb], 0, 0, 0);
    }
  }
}

// ============ merged: fused xq+LN1+Q-projection (bid<1172) OR K/V proj (bid>=1172) ====
// R13: LN1 quad-parallel (4 rows in flight, 4-step shfl within 16 lanes).
__global__ __launch_bounds__(256, 4) void k_qnpkv(
    const int* __restrict__ tq, const float* __restrict__ spatial,
    const float* __restrict__ temporal, const float* __restrict__ g,
    const float* __restrict__ bt, const ushort_t* __restrict__ wqs,
    const float* __restrict__ bq, ushort_t* __restrict__ Out,
    const ushort_t* __restrict__ xkb, const ushort_t* __restrict__ wks,
    const ushort_t* __restrict__ wvs, const float* __restrict__ bk,
    const float* __restrict__ bv, ushort_t* __restrict__ Kb,
    ushort_t* __restrict__ Vb)
{
  __shared__ ushort_t aT[64 * 256];    // A frags, then reused as epilogue tile
  const int NQ = cNN / 64;             // 1172
  const int tid = threadIdx.x, lane = tid & 63, w = tid >> 6;
  const int lane15 = lane & 15, kq = lane >> 4;
  f32x4 z = {0.f, 0.f, 0.f, 0.f};

  if ((int)blockIdx.x >= NQ) {
    // ---- K/V projection path
    int bid2 = blockIdx.x - NQ;        // 0..63
    const ushort_t* Ws = (bid2 >> 5) ? wvs : wks;
    const float* Bi = (bid2 >> 5) ? bv : bk;
    ushort_t* Kv = (bid2 >> 5) ? Vb : Kb;
    const int bx = bid2 & 31;
    const int rt0 = bx * 4, row0 = bx * 64;
    f32x4 c[4][4];
    #pragma unroll
    for (int mf = 0; mf < 4; ++mf)
      #pragma unroll
      for (int nb = 0; nb < 4; ++nb) c[mf][nb] = z;
    gemm_k256(xkb, Ws, rt0, w * 4, 16, lane, c);
    #pragma unroll
    for (int nb = 0; nb < 4; ++nb) {
      int col = w * 64 + nb * 16 + lane15;
      float bias = Bi[col];
      #pragma unroll
      for (int mf = 0; mf < 4; ++mf)
        #pragma unroll
        for (int i = 0; i < 4; ++i) {
          int row = row0 + mf * 16 + kq * 4 + i;
          Kv[(size_t)row * 256 + col] = f2bf(c[mf][nb][i] + bias);
        }
    }
    return;
  }

  // ---- xq + LN1 + Q-projection path
  const int rt0 = blockIdx.x * 4, row0 = blockIdx.x * 64;
  {
    int q = rt0 + w;                   // wave-uniform
    int s = q / cHW, hw = q % cHW;
    const int quad4 = lane >> 4;       // row within group of 4
    #pragma unroll 1
    for (int rrg = 0; rrg < 4; ++rrg) {
      int rr = rrg * 4 + quad4;
      int t = tq[s * cB + rr];
      float4 v[4];
      float sum = 0.f, sum2 = 0.f;
      #pragma unroll
      for (int ch = 0; ch < 4; ++ch) {
        int c0 = ch * 64 + lane15 * 4;
        float4 tv = *(const float4*)(temporal + (size_t)t * cC + c0);
        float4 sv = *(const float4*)(spatial + (size_t)hw * cC + c0);
        float4 vv;
        vv.x = tv.x + sv.x; vv.y = tv.y + sv.y;
        vv.z = tv.z + sv.z; vv.w = tv.w + sv.w;
        v[ch] = vv;
        sum  += vv.x + vv.y + vv.z + vv.w;
        sum2 += vv.x * vv.x + vv.y * vv.y + vv.z * vv.z + vv.w * vv.w;
      }
      #pragma unroll
      for (int off = 8; off >= 1; off >>= 1) {
        sum  += __shfl_xor(sum,  off, 64);
        sum2 += __shfl_xor(sum2, off, 64);
      }
      float mean = sum * (1.0f / cC);
      float var  = sum2 * (1.0f / cC) - mean * mean;
      float inv  = rsqrtf(var + 1e-5f);
      #pragma unroll
      for (int ch = 0; ch < 4; ++ch) {
        int c0 = ch * 64 + lane15 * 4;
        float4 g4 = *(const float4*)(g + c0);
        float4 b4 = *(const float4*)(bt + c0);
        int kc = c0 >> 5, qq = (c0 >> 3) & 3, joff = c0 & 7;
        ushort_t o[4] = {f2bf((v[ch].x - mean) * inv * g4.x + b4.x),
                         f2bf((v[ch].y - mean) * inv * g4.y + b4.y),
                         f2bf((v[ch].z - mean) * inv * g4.z + b4.z),
                         f2bf((v[ch].w - mean) * inv * g4.w + b4.w)};
        *(uint2*)&aT[(((w * 8 + kc) * 64) + qq * 16 + rr) * 8 + joff] = *(uint2*)o;
      }
    }
  }
  __syncthreads();
  f32x4 c[4][4];
  #pragma unroll
  for (int mf = 0; mf < 4; ++mf)
    #pragma unroll
    for (int nb = 0; nb < 4; ++nb) c[mf][nb] = z;
  gemm_k256(aT, wqs, 0, w * 4, 16, lane, c);
  __syncthreads();                     // all aT frag reads complete
  #pragma unroll
  for (int nb = 0; nb < 4; ++nb) {
    int col = w * 64 + nb * 16 + lane15;
    float bias = bq[col];
    #pragma unroll
    for (int mf = 0; mf < 4; ++mf)
      #pragma unroll
      for (int i = 0; i < 4; ++i)
        aT[(mf * 16 + kq * 4 + i) * 256 + col] = f2bf(c[mf][nb][i] + bias);
  }
  __syncthreads();
  uint2* outp = (uint2*)(Out + (size_t)row0 * 256);
  #pragma unroll
  for (int it = 0; it < 16; ++it) {
    int f = tid + it * 256;
    int row = f >> 6, c0 = (f & 63) * 4;
    outp[f] = *(uint2*)&aT[row * 256 + c0];
  }
}

// ============ MEGA-FUSED: wo proj + xq resid + LN2 + FFN1 + GELU + FFN2 + resid
//              + table/hand heads (fused from k_thg) ====
// R15: FULL operand swap. Phase-1 and FFN2 compute cc[cf][rf] = D[col][row]
// (col = w*32+cf*16+kq*4+i — 4 CONSECUTIVE cols/thread; row = rf*16+lane15).
// Consequences: bias+xq loads are float4 (was 64 scalars), LN2 row-reduce is a
// 2-step shfl (xor 16/32), phase-3 aT writes and phase-5 staging are uint2
// (was 32 ds_write_b16 each). FFN1/GELU identical to R14. Register-neutral
// (cc still 32 accs). Do not deepen per-block pipelining (R2/R11).
__global__ __launch_bounds__(512, 8) void k_woffn(
    const ushort_t* __restrict__ A, const ushort_t* __restrict__ wos,
    const float* __restrict__ bo, const int* __restrict__ tq,
    const float* __restrict__ spatial, const float* __restrict__ temporal,
    const float* __restrict__ g, const float* __restrict__ bt,
    const ushort_t* __restrict__ w1s, const float* __restrict__ b1,
    const ushort_t* __restrict__ w2s, const float* __restrict__ b2,
    ushort_t* __restrict__ x2out,
    const ushort_t* __restrict__ tws, const float* __restrict__ tb,
    const ushort_t* __restrict__ hws, const float* __restrict__ hb,
    float* __restrict__ out)
{
  __shared__ ushort_t aT[64 * 264];     // frag use: first 16384 elems; epilogue stride 264
  __shared__ ushort_t hL0[64 * 128];    // h ping buffer (16KB); LN2 scratch aliased
  __shared__ ushort_t hL1[64 * 128];    // h pong buffer (16KB)
  float (*red)[64][2] = (float (*)[64][2])hL0;       // 8*64*2*4 = 4096 B
  float* meanL = (float*)hL0 + 1024;                 // +4096 B
  float* invL  = meanL + 64;                         // ends < 16384
  const int tid = threadIdx.x, lane = tid & 63, w = tid >> 6;   // w in [0,8)
  const int lane15 = lane & 15, kq = lane >> 4;
  const int rt0 = blockIdx.x * 4, row0 = blockIdx.x * 64;
  const f32x4 z = {0.f, 0.f, 0.f, 0.f};

  // ---- Phase 1 (SWAPPED): cc[cf][rf] = D[col][row]; wo GEMM
  f32x4 cc[2][4];   // wo-GEMM -> residual carrier -> FFN2 accumulates ON TOP
  #pragma unroll
  for (int cf = 0; cf < 2; ++cf)
    #pragma unroll
    for (int rf = 0; rf < 4; ++rf) cc[cf][rf] = z;
  #pragma unroll 1
  for (int kc = 0; kc < 8; ++kc) {
    short8 a[4];
    #pragma unroll
    for (int rf = 0; rf < 4; ++rf)
      a[rf] = *(const short8*)(A + (((size_t)(rt0 + rf) * 8 + kc) * 64 + lane) * 8);
    #pragma unroll
    for (int cf = 0; cf < 2; ++cf) {
      short8 bw = *(const short8*)(wos + (((size_t)kc * 16 + w * 2 + cf) * 64 + lane) * 8);
      #pragma unroll
      for (int rf = 0; rf < 4; ++rf)
        cc[cf][rf] = __builtin_amdgcn_mfma_f32_16x16x32_bf16(bw, a[rf], cc[cf][rf], 0, 0, 0);
    }
  }
  // ---- + bias + xq (vectorized): cc now holds the residual x in f32
  {
    int trow[4], hwr[4];
    #pragma unroll
    for (int rf = 0; rf < 4; ++rf) {
      int q = rt0 + rf;
      int s = q / cHW;
      hwr[rf] = q % cHW;
      trow[rf] = tq[s * cB + lane15];
    }
    #pragma unroll
    for (int cf = 0; cf < 2; ++cf) {
      int col0 = w * 32 + cf * 16 + kq * 4;
      float4 b4 = *(const float4*)(bo + col0);
      #pragma unroll
      for (int rf = 0; rf < 4; ++rf) {
        float4 tv = *(const float4*)(temporal + (size_t)trow[rf] * cC + col0);
        float4 sv = *(const float4*)(spatial + (size_t)hwr[rf] * cC + col0);
        cc[cf][rf][0] += b4.x + tv.x + sv.x;
        cc[cf][rf][1] += b4.y + tv.y + sv.y;
        cc[cf][rf][2] += b4.z + tv.z + sv.z;
        cc[cf][rf][3] += b4.w + tv.w + sv.w;
      }
    }
  }
  // ---- Phase 2: LN2 stats. Thread holds 8 cols of row rf*16+lane15;
  // reduce across kq (shfl xor 16/32), then across waves via LDS.
  #pragma unroll
  for (int rf = 0; rf < 4; ++rf) {
    float s4 = 0.f, q4 = 0.f;
    #pragma unroll
    for (int cf = 0; cf < 2; ++cf)
      #pragma unroll
      for (int i = 0; i < 4; ++i) {
        float v = cc[cf][rf][i];
        s4 += v; q4 += v * v;
      }
    s4 += __shfl_xor(s4, 16, 64); q4 += __shfl_xor(q4, 16, 64);
    s4 += __shfl_xor(s4, 32, 64); q4 += __shfl_xor(q4, 32, 64);
    if (kq == 0) {
      red[w][rf * 16 + lane15][0] = s4;
      red[w][rf * 16 + lane15][1] = q4;
    }
  }
  __syncthreads();
  if (tid < 64) {
    float S = 0.f, Q = 0.f;
    #pragma unroll
    for (int ww = 0; ww < 8; ++ww) { S += red[ww][tid][0]; Q += red[ww][tid][1]; }
    float m = S * (1.0f / cC);
    float v = Q * (1.0f / cC) - m * m;
    meanL[tid] = m;
    invL[tid] = rsqrtf(v + 1e-5f);
  }
  __syncthreads();
  // ---- Phase 3: xln -> aT frag layout, VECTORIZED (uint2 per cf,rf)
  #pragma unroll
  for (int cf = 0; cf < 2; ++cf) {
    int col0 = w * 32 + cf * 16 + kq * 4;
    float4 g4 = *(const float4*)(g + col0);
    float4 bb4 = *(const float4*)(bt + col0);
    int qq = cf * 2 + (kq >> 1);
    int j0 = (kq & 1) * 4;
    #pragma unroll
    for (int rf = 0; rf < 4; ++rf) {
      int row = rf * 16 + lane15;
      float m = meanL[row], iv = invL[row];
      ushort_t o[4];
      o[0] = f2bf((cc[cf][rf][0] - m) * iv * g4.x + bb4.x);
      o[1] = f2bf((cc[cf][rf][1] - m) * iv * g4.y + bb4.y);
      o[2] = f2bf((cc[cf][rf][2] - m) * iv * g4.z + bb4.z);
      o[3] = f2bf((cc[cf][rf][3] - m) * iv * g4.w + bb4.w);
      *(uint2*)&aT[(((rf * 8 + w) * 64) + qq * 16 + lane15) * 8 + j0] = *(uint2*)o;
    }
  }
  __syncthreads();                     // aT ready; meanL/invL dead (hL0 reusable)
  // ---- Phase 4: FFN loop, 8 chunks of 128 h-cols; h ping-pong hL0/hL1.
  #pragma unroll 1
  for (int hc2 = 0; hc2 < 8; ++hc2) {
    ushort_t* hB = (hc2 & 1) ? hL1 : hL0;
    // FFN1 (SWAPPED, R14): c1[xt] = D[h-col][x-row].
    f32x4 c1[4];
    #pragma unroll
    for (int xt = 0; xt < 4; ++xt) c1[xt] = z;
    const int slot = hc2 * 8 + w;
    #pragma unroll 1
    for (int kc = 0; kc < 8; ++kc) {
      short8 wf = *(const short8*)(w1s + (((size_t)kc * 64 + slot) * 64 + lane) * 8);
      #pragma unroll
      for (int xt = 0; xt < 4; ++xt) {
        short8 a = *(const short8*)&aT[((xt * 8 + kc) * 64 + lane) * 8];
        c1[xt] = __builtin_amdgcn_mfma_f32_16x16x32_bf16(wf, a, c1[xt], 0, 0, 0);
      }
    }
    // GELU = x * sigmoid(2u) [exact identity]; one ds_write_b64 per xt.
    {
      float4 b4 = *(const float4*)(b1 + hc2 * 128 + w * 16 + kq * 4);
      const int base = (w >> 1) * 2048 + (((w * 2) + (kq >> 1)) & 3) * 128
                     + lane15 * 8 + (kq & 1) * 4;
      #pragma unroll
      for (int xt = 0; xt < 4; ++xt) {
        ushort_t o[4];
        #pragma unroll
        for (int i = 0; i < 4; ++i) {
          float xx = c1[xt][i] + ((const float*)&b4)[i];
          float x2v = xx * xx;
          float mm = fmaf(x2v, 0.044715f, 1.0f);
          float u2 = xx * mm * -1.5957691216057308f;   // -2*sqrt(2/pi)
          float e = __expf(u2);
          float ge = xx * __builtin_amdgcn_rcpf(1.0f + e);
          o[i] = f2bf(ge);
        }
        *(uint2*)&hB[base + xt * 512] = *(uint2*)o;
      }
    }
    __syncthreads();                  // hB chunk ready
    // FFN2 (SWAPPED): cc[cf][rf] += mfma(w2_frag(colblk), h_frag(rowblk))
    #pragma unroll 1
    for (int kc2 = 0; kc2 < 4; ++kc2) {
      short8 a2[4];
      #pragma unroll
      for (int rf = 0; rf < 4; ++rf)
        a2[rf] = *(const short8*)&hB[((kc2 * 4 + rf) * 64 + lane) * 8];
      #pragma unroll
      for (int cf = 0; cf < 2; ++cf) {
        short8 bw = *(const short8*)(w2s +
            (((size_t)(hc2 * 4 + kc2) * 16 + w * 2 + cf) * 64 + lane) * 8);
        #pragma unroll
        for (int rf = 0; rf < 4; ++rf)
          cc[cf][rf] = __builtin_amdgcn_mfma_f32_16x16x32_bf16(bw, a2[rf], cc[cf][rf], 0, 0, 0);
      }
    }
  }
  __syncthreads();                     // all aT/hL frag reads complete
  // ---- Phase 5: cc (= x + FFN) + b2 -> aT stride 264, VECTORIZED
  #pragma unroll
  for (int cf = 0; cf < 2; ++cf) {
    int col0 = w * 32 + cf * 16 + kq * 4;
    float4 b4 = *(const float4*)(b2 + col0);
    #pragma unroll
    for (int rf = 0; rf < 4; ++rf) {
      ushort_t o[4];
      o[0] = f2bf(cc[cf][rf][0] + b4.x);
      o[1] = f2bf(cc[cf][rf][1] + b4.y);
      o[2] = f2bf(cc[cf][rf][2] + b4.z);
      o[3] = f2bf(cc[cf][rf][3] + b4.w);
      *(uint2*)&aT[(rf * 16 + lane15) * 264 + col0] = *(uint2*)o;
    }
  }
  __syncthreads();
  // ---- gx-row x2 write (only rows the gx kernel reads: q%293==292)
  #pragma unroll
  for (int mf = 0; mf < 4; ++mf) {
    if ((rt0 + mf) % cHW == 292) {
      for (int f = tid; f < 1024; f += 512) {
        int rl = mf * 16 + (f >> 6), c4 = (f & 63) * 4;
        *(uint2*)&x2out[(size_t)(row0 + rl) * 256 + c4] = *(uint2*)&aT[rl * 264 + c4];
      }
    }
  }
  // ---- fused table/hand heads: waves 0-3 table (rows (w&3)*16), 4-7 hand
  {
    const int wl = w & 3;
    const bool isHand = (w >= 4);
    const ushort_t* Ws = isHand ? hws : tws;
    const float* Bi = isHand ? hb : tb;
    f32x4 ct[2];
    ct[0] = z; ct[1] = z;
    const ushort_t* arow = aT + (wl * 16 + lane15) * 264 + kq * 8;
    #pragma unroll
    for (int kc = 0; kc < 8; ++kc) {
      short8 a = *(const short8*)(arow + kc * 32);
      #pragma unroll
      for (int nb = 0; nb < 2; ++nb) {
        short8 bf_ = *(const short8*)(Ws + (((size_t)(kc * 2 + nb)) * 64 + lane) * 8);
        ct[nb] = __builtin_amdgcn_mfma_f32_16x16x32_bf16(a, bf_, ct[nb], 0, 0, 0);
      }
    }
    #pragma unroll
    for (int nb = 0; nb < 2; ++nb) {
      int j = nb * 16 + lane15;
      float bias = Bi[j];
      int uh = j >> 3, uw = (j >> 1) & 3, uc = j & 1;
      #pragma unroll
      for (int i = 0; i < 4; ++i) {
        int rg = row0 + wl * 16 + kq * 4 + i;
        int b = rg & 15, q = rg >> 4;
        int s = (q * 3579) >> 20;          // exact q/293 for q<14768
        int hw = q - s * cHW;
        if (!isHand && hw < 256) {
          int th = hw >> 4, twi = hw & 15;
          size_t idx = TX_OFF +
              ((((size_t)(s * cB + b)) * 2 + uc) * 64 + (th * 4 + uh)) * 64 + (twi * 4 + uw);
          out[idx] = ct[nb][i] + bias;
        } else if (isHand && hw >= 256 && hw < 292) {
          int h2 = hw - 256;
          int hh = h2 / 6, ww = h2 % 6;
          size_t idx = HX_OFF +
              ((((size_t)(s * cB + b)) * 2 + uc) * 24 + (hh * 4 + uh)) * 24 + (ww * 4 + uw);
          out[idx] = ct[nb][i] + bias;
        }
      }
    }
  }
}

// ============ MFMA attention: 512 threads, per (b,h), 16 q-tiles per block ============
__global__ __launch_bounds__(512, 4) void k_attn(
    const ushort_t* __restrict__ Qb, const ushort_t* __restrict__ Kb,
    const ushort_t* __restrict__ Vb, const int* __restrict__ tq,
    const int* __restrict__ tk, const int* __restrict__ pad_q,
    const int* __restrict__ pad_k, ushort_t* __restrict__ aout)
{
  __shared__ ushort_t KL[128 * 72];     // [k][d]
  __shared__ ushort_t VtL[64 * 136];    // [d][k]
  __shared__ ushort_t pL[8][16 * 136];  // per-wave P tile
  __shared__ int tkL[128];

  const int h = blockIdx.y, b = blockIdx.z;
  const int tid = threadIdx.x, lane = tid & 63, w = tid >> 6;   // w in [0,8)
  const int m15 = lane & 15, quad = lane >> 4;

  for (int i = tid; i < 128 * 16; i += 512) {
    int k = i >> 4, d4 = (i & 15) * 4;
    size_t src = (size_t)(k * cB + b) * 256 + h * 64 + d4;
    uint2 kv = *(const uint2*)&Kb[src];
    uint2 vv = *(const uint2*)&Vb[src];
    *(uint2*)&KL[k * 72 + d4] = kv;
    const ushort_t* vvp = (const ushort_t*)&vv;
    #pragma unroll
    for (int t = 0; t < 4; ++t) VtL[(d4 + t) * 136 + k] = vvp[t];
  }
  if (tid < 128) tkL[tid] = tk[tid * cB + b];
  __syncthreads();
  const int pk = pad_k[b];
  const int pq = pad_q[b] * cHW;
  ushort_t* pRow = pL[w];
  const f32x4 z = {0.f, 0.f, 0.f, 0.f};

  for (int pr = 0; pr < 2; ++pr) {
    int qt = blockIdx.x * 16 + pr * 8 + w;
    if (qt >= 293) break;                       // wave-uniform
    const ushort_t* qrow =
        Qb + ((size_t)((qt * 16 + m15) * cB + b)) * 256 + h * 64 + quad * 8;
    short8 qa0 = *(const short8*)(qrow);
    short8 qa1 = *(const short8*)(qrow + 32);
    f32x4 s[8];
    #pragma unroll
    for (int nf = 0; nf < 8; ++nf) {
      const ushort_t* kp = KL + (nf * 16 + m15) * 72 + quad * 8;
      short8 b0 = *(const short8*)(kp);
      short8 b1 = *(const short8*)(kp + 32);
      s[nf] = __builtin_amdgcn_mfma_f32_16x16x32_bf16(qa0, b0, z, 0, 0, 0);
      s[nf] = __builtin_amdgcn_mfma_f32_16x16x32_bf16(qa1, b1, s[nf], 0, 0, 0);
    }
    int tqv[4], qok[4];
    #pragma unroll
    for (int i = 0; i < 4; ++i) {
      int qg = qt * 16 + quad * 4 + i;
      int sidx = (qg * 3579) >> 20;            // exact q/293 for q<14768
      tqv[i] = tq[sidx * cB + b];
      qok[i] = (qg < pq);
    }
    #pragma unroll
    for (int nf = 0; nf < 8; ++nf) {
      int kidx = nf * 16 + m15;
      int tkc = tkL[kidx];
      bool kok = (kidx < pk);
      #pragma unroll
      for (int i = 0; i < 4; ++i) {
        bool ok = kok && qok[i] && (tkc <= tqv[i]);
        s[nf][i] = ok ? s[nf][i] * 0.125f : -1e9f;
      }
    }
    float mx[4], l[4];
    #pragma unroll
    for (int i = 0; i < 4; ++i) {
      float m = s[0][i];
      #pragma unroll
      for (int nf = 1; nf < 8; ++nf) m = fmaxf(m, s[nf][i]);
      #pragma unroll
      for (int off = 8; off >= 1; off >>= 1) m = fmaxf(m, __shfl_xor(m, off, 64));
      mx[i] = m;
    }
    #pragma unroll
    for (int i = 0; i < 4; ++i) l[i] = 0.f;
    #pragma unroll
    for (int nf = 0; nf < 8; ++nf)
      #pragma unroll
      for (int i = 0; i < 4; ++i) {
        float p = __expf(s[nf][i] - mx[i]);
        s[nf][i] = p;
        l[i] += p;
      }
    #pragma unroll
    for (int i = 0; i < 4; ++i) {
      float t = l[i];
      #pragma unroll
      for (int off = 8; off >= 1; off >>= 1) t += __shfl_xor(t, off, 64);
      l[i] = 1.0f / t;
    }
    #pragma unroll
    for (int nf = 0; nf < 8; ++nf)
      #pragma unroll
      for (int i = 0; i < 4; ++i)
        pRow[(quad * 4 + i) * 136 + nf * 16 + m15] = f2bf(s[nf][i]);
    f32x4 o[4];
    #pragma unroll
    for (int nf = 0; nf < 4; ++nf) o[nf] = z;
    #pragma unroll
    for (int kc = 0; kc < 4; ++kc) {
      short8 pa = *(const short8*)(pRow + m15 * 136 + kc * 32 + quad * 8);
      #pragma unroll
      for (int nf = 0; nf < 4; ++nf) {
        short8 vb = *(const short8*)(VtL + (nf * 16 + m15) * 136 + kc * 32 + quad * 8);
        o[nf] = __builtin_amdgcn_mfma_f32_16x16x32_bf16(pa, vb, o[nf], 0, 0, 0);
      }
    }
    #pragma unroll
    for (int nf = 0; nf < 4; ++nf) {
      int c = h * 64 + nf * 16 + m15;
      size_t base = ((size_t)(c >> 5)) * 64 + ((c >> 3) & 3) * 16 + b;
      int cj = c & 7;
      #pragma unroll
      for (int i = 0; i < 4; ++i) {
        int qg = qt * 16 + quad * 4 + i;
        aout[(((size_t)qg * 8) * 64 + base) * 8 + cj] = f2bf(o[nf][i] * l[i]);
      }
    }
  }
}

// ============ gx heads only (table/hand heads fused into k_woffn) ============
__global__ __launch_bounds__(256, 4) void k_thg(
    const ushort_t* __restrict__ x2,
    const float* __restrict__ mw, const float* __restrict__ mbi,
    const float* __restrict__ sw, const float* __restrict__ sbi,
    const float* __restrict__ cw, const float* __restrict__ cbi,
    float* __restrict__ out)
{
  __shared__ float rowL[256];
  const int tid = threadIdx.x;
  int sb = blockIdx.x;                 // s*16 + b
  int s = sb >> 4, b = sb & 15;
  const ushort_t* row = x2 + ((size_t)(s * cHW + 292) * cB + b) * cC;
  rowL[tid] = bf2f(row[tid]);
  __syncthreads();
  int j = tid;
  if (j < 100) {
    const float* W;
    const float* Bi;
    int jj, M;
    size_t off;
    if (j < 20)      { W = mw; Bi = mbi; jj = j;      M = 20; off = 0;     }
    else if (j < 84) { W = sw; Bi = sbi; jj = j - 20; M = 64; off = 5120;  }
    else             { W = cw; Bi = cbi; jj = j - 84; M = 16; off = 21504; }
    float acc = Bi[jj];
    for (int c = 0; c < 256; ++c) acc = fmaf(rowL[c], W[c * M + jj], acc);
    out[off + (size_t)sb * M + jj] = acc;
  }
}

extern "C" void kernel_launch(void* const* d_in, const int* in_sizes, int n_in,
                              void* d_out, int out_size, void* d_ws, size_t ws_size,
                              hipStream_t stream)
{
  const int*   tq       = (const int*)d_in[0];
  const int*   pad_q    = (const int*)d_in[1];
  const float* xk       = (const float*)d_in[2];
  const int*   tk       = (const int*)d_in[3];
  const int*   pad_k    = (const int*)d_in[4];
  const float* spatial  = (const float*)d_in[8];
  const float* temporal = (const float*)d_in[9];
  const float* ln1_g    = (const float*)d_in[10];
  const float* ln1_b    = (const float*)d_in[11];
  const float* wq       = (const float*)d_in[12];
  const float* bq       = (const float*)d_in[13];
  const float* wk       = (const float*)d_in[14];
  const float* bk       = (const float*)d_in[15];
  const float* wv       = (const float*)d_in[16];
  const float* bv       = (const float*)d_in[17];
  const float* wo       = (const float*)d_in[18];
  const float* bo       = (const float*)d_in[19];
  const float* ln2_g    = (const float*)d_in[20];
  const float* ln2_b    = (const float*)d_in[21];
  const float* w1       = (const float*)d_in[22];
  const float* b1       = (const float*)d_in[23];
  const float* w2       = (const float*)d_in[24];
  const float* b2       = (const float*)d_in[25];
  const float* table_w  = (const float*)d_in[26];
  const float* table_b  = (const float*)d_in[27];
  const float* hand_w   = (const float*)d_in[28];
  const float* hand_b   = (const float*)d_in[29];
  const float* mode_w   = (const float*)d_in[30];
  const float* mode_b   = (const float*)d_in[31];
  const float* shape_w  = (const float*)d_in[32];
  const float* shape_b  = (const float*)d_in[33];
  const float* color_w  = (const float*)d_in[34];
  const float* color_b  = (const float*)d_in[35];
  float* out = (float*)d_out;

  char* ws = (char*)d_ws;
  const size_t NB2 = (size_t)cNN * cC * sizeof(ushort_t);      // 38,404,096
  ushort_t* buf1 = (ushort_t*)ws;                              // a_swz (attn out)
  ushort_t* buf2 = (ushort_t*)(ws + NB2);                      // Q -> x2 (gx rows)
  char* p = ws + 2 * NB2;
  ushort_t* Kb  = (ushort_t*)p;  p += (size_t)cLK * cB * 256 * 2;
  ushort_t* Vb  = (ushort_t*)p;  p += (size_t)cLK * cB * 256 * 2;
  ushort_t* xkb = (ushort_t*)p;  p += (size_t)cLK * cB * 256 * 2;
  ushort_t* wqs = (ushort_t*)p;  p += 256 * 256 * 2;
  ushort_t* wks = (ushort_t*)p;  p += 256 * 256 * 2;
  ushort_t* wvs = (ushort_t*)p;  p += 256 * 256 * 2;
  ushort_t* wos = (ushort_t*)p;  p += 256 * 256 * 2;
  ushort_t* w1s = (ushort_t*)p;  p += 256 * 1024 * 2;
  ushort_t* w2s = (ushort_t*)p;  p += 1024 * 256 * 2;
  ushort_t* tws = (ushort_t*)p;  p += 256 * 32 * 2;
  ushort_t* hws = (ushort_t*)p;  p += 256 * 32 * 2;

  k_prep<<<904, 256, 0, stream>>>(xk, xkb, wq, wqs, wk, wks, wv, wvs,
                                  wo, wos, w1, w1s, w2, w2s,
                                  table_w, tws, hand_w, hws);
  k_qnpkv<<<cNN / 64 + 64, 256, 0, stream>>>(tq, spatial, temporal, ln1_g, ln1_b,
                                             wqs, bq, buf2, xkb, wks, wvs,
                                             bk, bv, Kb, Vb);
  k_attn<<<dim3(19, cH, cB), 512, 0, stream>>>(buf2, Kb, Vb, tq, tk,
                                               pad_q, pad_k, buf1);
  k_woffn<<<cNN / 64, 512, 0, stream>>>(buf1, wos, bo, tq, spatial, temporal,
                                        ln2_g, ln2_b, w1s, b1, w2s, b2, buf2,
                                        tws, table_b, hws, hand_b, out);
  k_thg<<<cS * cB, 256, 0, stream>>>(buf2, mode_w, mode_b, shape_w, shape_b,
                                     color_w, color_b, out);
}